// Round 6
// baseline (393.273 us; speedup 1.0000x reference)
//
#include <hip/hip_runtime.h>
#include <math.h>

#define MUL 32
#define NATTR 4
#define NBASIS 10
#define HID 64
#define OUT_DIM 16
#define NGRAPH 8
#define NT 513      // w(len) table entries: len = i/128, i in [0,512]

#define PI_F 3.14159265358979323846f
#define SQRT3_F 1.7320508075688772f
#define INV_SQRT3_F 0.5773502691896258f
#define INV_SQRT10_F 0.31622776601683794f
#define INV_SQRTNN_F 0.17677669529663687f   // 1/sqrt(32)
#define NORM128_F 0.08838834764831845f      // 1/sqrt(128)
#define NORM256_F 0.0625f                   // 1/sqrt(256)
#define C_S_F 0.3826834323650898f           // sin(pi/8)
#define C_X_F 0.9238795325112867f           // cos(pi/8)
#define CSTEP_F (4.0f/9.0f)                 // linspace(0,4,10) step

#define ACC_CAP 8   // LDS accumulator: max node range per 128-slot block (fast path)

__device__ inline unsigned short f2bf(float x) {
    unsigned u = __float_as_uint(x);
    u += 0x7FFF + ((u >> 16) & 1);          // round-to-nearest-even
    return (unsigned short)(u >> 16);
}
__device__ inline float bf2f(unsigned short h) {
    return __uint_as_float(((unsigned)h) << 16);
}

// ---------------------------------------------------------------- bodies
__device__ __forceinline__ void init_sv_body(
    int blk, const float* __restrict__ x,
    float* __restrict__ s, float* __restrict__ v, int N) {
    int i = blk * 256 + threadIdx.x;
    if (i >= N * 128) return;
    int n = i >> 7, c = i & 127;
    float val = x[i];
    if (c < 32) s[n * 32 + c] = val;
    else        v[n * 96 + (c - 32)] = val;
}

__device__ __forceinline__ void setup_weights_body(
    int blk,
    const float* __restrict__ Wsc0, const float* __restrict__ Wl10,
    const float* __restrict__ Wsc1, const float* __restrict__ Wl11,
    const float* __restrict__ Wl20, const float* __restrict__ Wl21,
    float* __restrict__ Wfp, unsigned* __restrict__ Wupk) {
    int i = blk * 256 + threadIdx.x;
    if (i < 32768) {
        int idx = i >> 12;          // l*4 + m
        int r = i & 4095;
        int l = idx >> 2, m = idx & 3;
        const float* base = (m == 0 ? Wsc0 : m == 1 ? Wl10 : m == 2 ? Wsc1 : Wl11)
                            + l * 4096;
        int u = r >> 7, rr = r & 127, a = rr >> 5, ww = rr & 31;
        Wfp[idx * 4096 + u * 128 + ww * 4 + a] = base[r];
    } else if (i < 49152) {
        int j = i - 32768;
        int l = j >> 13;
        int r = j & 8191;
        int u = r >> 7, rr = r & 127, a = rr >> 5, ww = rr & 31;
        unsigned lo = f2bf(Wl20[l * 8192 + r]);
        unsigned hi = f2bf(Wl21[l * 8192 + r]);
        Wupk[l * 8192 + u * 128 + ww * 4 + a] = lo | (hi << 16);
    }
}

// w(len) table generator: tab[l][i][j] = pack(w_flat[j], w_flat[64+j]) at len=i/128
// (j<32 -> roles (w0,w2); j>=32 with u=j-32 -> (w1,w3); both collapse to (j, 64+j))
__device__ __forceinline__ void tab_gen_body(
    int blk, const float* __restrict__ Wfc1, const float* __restrict__ Wfc2,
    unsigned* __restrict__ tab) {
    int id = blk * 256 + threadIdx.x;
    if (id >= 2 * NT * 8) return;
    int l = id / (NT * 8);
    int r = id % (NT * 8);
    int i = r >> 3, cg = r & 7;
    float len = (float)i * (1.0f / 128.0f);
    float uu = len * 0.5f - 2.0f;
    float cut = (uu > 0.0f) ? 0.0f
              : ((uu < -1.0f) ? 1.0f : 0.5f * (1.0f - __cosf(PI_F * uu)));
    float emb[10];
#pragma unroll
    for (int k = 0; k < 10; k++) {
        float d = (len - k * CSTEP_F) * 2.5f;
        emb[k] = __expf(-d * d) * cut;
    }
    float h[64];
    const float* W1 = Wfc1 + l * 640;
#pragma unroll
    for (int n = 0; n < 64; n++) {
        float a = 0.f;
#pragma unroll
        for (int k = 0; k < 10; k++) a += emb[k] * W1[k * 64 + n];
        a *= INV_SQRT10_F;
        h[n] = a / (1.0f + __expf(-a));
    }
    const float* W2 = Wfc2 + l * 8192;
    unsigned* trow = tab + (size_t)l * NT * 64 + i * 64;
    for (int jj = 0; jj < 8; jj++) {
        int j = cg * 8 + jj;
        float w0 = 0.f, w1 = 0.f;
#pragma unroll
        for (int n = 0; n < 64; n++) {
            float hn = h[n];
            w0 += hn * W2[n * 128 + j];
            w1 += hn * W2[n * 128 + 64 + j];
        }
        w0 *= 0.125f; w1 *= 0.125f;
        trow[j] = (unsigned)f2bf(w0) | ((unsigned)f2bf(w1) << 16);
    }
}

__device__ __forceinline__ void csr_count_body(
    int blk, const int* __restrict__ edst, int* __restrict__ cnt, int E) {
    int e = blk * 256 + threadIdx.x;
    if (e < E) atomicAdd(&cnt[edst[e]], 1);
}

__device__ __forceinline__ void csr_fill_body(
    int blk, const int* __restrict__ edst, const int* __restrict__ esrc,
    const float* __restrict__ edge_vec, int* __restrict__ cursor,
    float* __restrict__ vec_csr, int* __restrict__ slot_dst, int E) {
    int e = blk * 256 + threadIdx.x;
    if (e < E) {
        int d = edst[e];
        int p = atomicAdd(&cursor[d], 1);
        float4 vv = {edge_vec[e * 3 + 0], edge_vec[e * 3 + 1], edge_vec[e * 3 + 2],
                     __int_as_float(esrc[e])};
        *(float4*)(vec_csr + (size_t)p * 4) = vv;
        slot_dst[p] = d;
    }
}

// node fctp: 16 nodes/block; smem: [0,16K) w0 | [16K,32K) w1 | [32K,35K) sh
__device__ __forceinline__ void node_fctp_body(
    int blk, int path,
    const float* __restrict__ s, const float* __restrict__ v,
    const float* __restrict__ attr, const float* __restrict__ Wfp,
    float* __restrict__ sc_s, float* __restrict__ sc_v,
    float* __restrict__ xsv, int N, char* smem) {
    float* w0 = (float*)smem;
    float* w1 = (float*)(smem + 16384);
    float (*sh)[96] = (float(*)[96])(smem + 32768);
    int ln = threadIdx.x >> 5, w = threadIdx.x & 31;
    const float4* W0p = (const float4*)(Wfp + path * 8192);
    const float4* W1p = (const float4*)(Wfp + path * 8192 + 4096);
    for (int i = threadIdx.x; i < 1024; i += 256) {
        ((float4*)w0)[i] = W0p[i];
        ((float4*)w1)[i] = W1p[i];
    }
    for (int g = 0; g < 2; g++) {
        int n = blk * 16 + g * 8 + ln;
        bool valid = n < N;
        __syncthreads();
        if (valid) {
            if (path == 0) {
                sh[ln][w] = s[n * 32 + w];
            } else {
                sh[ln][w * 3 + 0] = v[n * 96 + w * 3 + 0];
                sh[ln][w * 3 + 1] = v[n * 96 + w * 3 + 1];
                sh[ln][w * 3 + 2] = v[n * 96 + w * 3 + 2];
            }
        }
        __syncthreads();
        if (!valid) continue;
        float4 at = *(const float4*)(attr + n * 4);
        if (path == 0) {
            float acc0 = 0.f, acc1 = 0.f;
            for (int u = 0; u < 32; u++) {
                float su = sh[ln][u];
                float4 W0v = *(const float4*)(w0 + u * 128 + w * 4);
                float4 W1v = *(const float4*)(w1 + u * 128 + w * 4);
                float d0 = at.x * W0v.x + at.y * W0v.y + at.z * W0v.z + at.w * W0v.w;
                float d1 = at.x * W1v.x + at.y * W1v.y + at.z * W1v.z + at.w * W1v.w;
                acc0 += su * d0;
                acc1 += su * d1;
            }
            sc_s[n * 32 + w] = acc0 * NORM128_F;
            xsv[(size_t)n * 128 + w * 4 + 3] = acc1 * NORM128_F;
        } else {
            float a00 = 0, a01 = 0, a02 = 0, a10 = 0, a11 = 0, a12 = 0;
            for (int u = 0; u < 32; u++) {
                float vu0 = sh[ln][u * 3 + 0];
                float vu1 = sh[ln][u * 3 + 1];
                float vu2 = sh[ln][u * 3 + 2];
                float4 W0v = *(const float4*)(w0 + u * 128 + w * 4);
                float4 W1v = *(const float4*)(w1 + u * 128 + w * 4);
                float d0 = at.x * W0v.x + at.y * W0v.y + at.z * W0v.z + at.w * W0v.w;
                float d1 = at.x * W1v.x + at.y * W1v.y + at.z * W1v.z + at.w * W1v.w;
                a00 += vu0 * d0; a01 += vu1 * d0; a02 += vu2 * d0;
                a10 += vu0 * d1; a11 += vu1 * d1; a12 += vu2 * d1;
            }
            sc_v[n * 96 + w * 3 + 0] = a00 * NORM128_F;
            sc_v[n * 96 + w * 3 + 1] = a01 * NORM128_F;
            sc_v[n * 96 + w * 3 + 2] = a02 * NORM128_F;
            float* xp = xsv + (size_t)n * 128 + w * 4;
            xp[0] = a10 * NORM128_F;
            xp[1] = a11 * NORM128_F;
            xp[2] = a12 * NORM128_F;
        }
    }
}

// node update: smem [0,32K) pk | [32K,34K) sh_as | [34K,40K) sh_av
__device__ __forceinline__ void node_update_body(
    int blk, const float* __restrict__ agg_s, const float* __restrict__ agg_v,
    const float* __restrict__ attr, const unsigned* __restrict__ Wupk,
    const float* __restrict__ sc_s, const float* __restrict__ sc_v,
    float* __restrict__ s, float* __restrict__ v, int N, char* smem) {
    unsigned* pk = (unsigned*)smem;
    float (*sh_as)[64]  = (float(*)[64])(smem + 32768);
    float (*sh_av)[192] = (float(*)[192])(smem + 32768 + 2048);
    int ln = threadIdx.x >> 5, w = threadIdx.x & 31;
    for (int i = threadIdx.x; i < 2048; i += 256)
        ((uint4*)pk)[i] = ((const uint4*)Wupk)[i];
    for (int g = 0; g < 2; g++) {
        int n = blk * 16 + g * 8 + ln;
        bool valid = n < N;
        __syncthreads();
        if (valid) {
            sh_as[ln][w] = agg_s[n * 64 + w];
            sh_as[ln][32 + w] = agg_s[n * 64 + 32 + w];
#pragma unroll
            for (int i = 0; i < 6; i++)
                sh_av[ln][w * 6 + i] = agg_v[(size_t)n * 192 + w * 6 + i];
        }
        __syncthreads();
        if (!valid) continue;
        float4 at = *(const float4*)(attr + n * 4);
        float acc_s = 0.f, a0 = 0.f, a1 = 0.f, a2 = 0.f;
        for (int u = 0; u < 64; u++) {
            float gs = sh_as[ln][u];
            float g0 = sh_av[ln][u * 3 + 0];
            float g1 = sh_av[ln][u * 3 + 1];
            float g2 = sh_av[ln][u * 3 + 2];
            uint4 pv = *(const uint4*)(pk + u * 128 + w * 4);
            float w20x = bf2f((unsigned short)pv.x), w21x = bf2f((unsigned short)(pv.x >> 16));
            float w20y = bf2f((unsigned short)pv.y), w21y = bf2f((unsigned short)(pv.y >> 16));
            float w20z = bf2f((unsigned short)pv.z), w21z = bf2f((unsigned short)(pv.z >> 16));
            float w20w = bf2f((unsigned short)pv.w), w21w = bf2f((unsigned short)(pv.w >> 16));
            float d0 = at.x * w20x + at.y * w20y + at.z * w20z + at.w * w20w;
            float d1 = at.x * w21x + at.y * w21y + at.z * w21z + at.w * w21w;
            acc_s += gs * d0;
            a0 += g0 * d1; a1 += g1 * d1; a2 += g2 * d1;
        }
        float os = acc_s * NORM256_F;
        float sn = C_S_F * sc_s[n * 32 + w] + C_X_F * os;
        float sig = 1.0f / (1.0f + __expf(-sn));
        s[n * 32 + w] += sn * sig;   // silu(sn)
        float ov0 = a0 * NORM256_F, ov1 = a1 * NORM256_F, ov2 = a2 * NORM256_F;
        v[n * 96 + w * 3 + 0] += (C_S_F * sc_v[n * 96 + w * 3 + 0] + C_X_F * ov0) * sig;
        v[n * 96 + w * 3 + 1] += (C_S_F * sc_v[n * 96 + w * 3 + 1] + C_X_F * ov1) * sig;
        v[n * 96 + w * 3 + 2] += (C_S_F * sc_v[n * 96 + w * 3 + 2] + C_X_F * ov2) * sig;
    }
}

// ---------------------------------------------------------------- mega kernels
__global__ __launch_bounds__(256) void mega1(
    int nInit, int nSetup, int nCount,
    const float* __restrict__ x, float* __restrict__ s, float* __restrict__ v,
    const float* __restrict__ Wfc1, const float* __restrict__ Wfc2,
    const float* __restrict__ Wsc0, const float* __restrict__ Wl10,
    const float* __restrict__ Wsc1, const float* __restrict__ Wl11,
    const float* __restrict__ Wl20, const float* __restrict__ Wl21,
    float* __restrict__ Wfp, unsigned* __restrict__ Wupk,
    unsigned* __restrict__ tab,
    const int* __restrict__ edst, int* __restrict__ cnt, int N, int E) {
    int b = blockIdx.x;
    if (b < nInit) { init_sv_body(b, x, s, v, N); return; }
    b -= nInit;
    if (b < nSetup) {
        setup_weights_body(b, Wsc0, Wl10, Wsc1, Wl11, Wl20, Wl21, Wfp, Wupk);
        return;
    }
    b -= nSetup;
    if (b < nCount) { csr_count_body(b, edst, cnt, E); return; }
    b -= nCount;
    tab_gen_body(b, Wfc1, Wfc2, tab);
}

__global__ void csr_scan(const int* __restrict__ cnt, int* __restrict__ off,
                         int* __restrict__ cursor, int N) {
    __shared__ int sums[256];
    int t = threadIdx.x;
    int chunk = (N + 255) / 256;
    int lo = t * chunk, hi = lo + chunk; if (hi > N) hi = N;
    int s = 0;
    for (int i = lo; i < hi; i++) s += cnt[i];
    sums[t] = s;
    __syncthreads();
    for (int d = 1; d < 256; d <<= 1) {
        int v = (t >= d) ? sums[t - d] : 0;
        __syncthreads();
        sums[t] += v;
        __syncthreads();
    }
    int run = (t == 0) ? 0 : sums[t - 1];
    for (int i = lo; i < hi; i++) {
        off[i] = run; cursor[i] = run;
        run += cnt[i];
    }
}

// csr_fill || fctp(layer0, both paths) || zero agg ping-pong buffers
__global__ __launch_bounds__(256, 4) void mega2(
    int nFill, int nF,
    const int* __restrict__ edst, const int* __restrict__ esrc,
    const float* __restrict__ edge_vec, int* __restrict__ cursor,
    float* __restrict__ vec_csr, int* __restrict__ slot_dst, int E,
    const float* __restrict__ s, const float* __restrict__ v,
    const float* __restrict__ attr, const float* __restrict__ Wfp,
    float* __restrict__ sc_s, float* __restrict__ sc_v,
    float* __restrict__ xsv, int N,
    float* __restrict__ zero_base, int nZeroF4) {
    __shared__ __align__(16) char smem[35840];
    int b = blockIdx.x;
    if (b < nFill) {
        csr_fill_body(b, edst, esrc, edge_vec, cursor, vec_csr, slot_dst, E);
        return;
    }
    b -= nFill;
    if (b < 2 * nF) {
        node_fctp_body(b % nF, b / nF, s, v, attr, Wfp, sc_s, sc_v, xsv, N, smem);
        return;
    }
    b -= 2 * nF;
    int i = b * 256 + threadIdx.x;
    if (i < nZeroF4) {
        float4 z = {0.f, 0.f, 0.f, 0.f};
        ((float4*)zero_base)[i] = z;
    }
}

// ---------------------------------------------------------------- msg kernel
// Table-driven edge weights + message + hierarchical reduction.
// 128 CSR slots/block. Phase A: w(len) via packed-bf16 table lerp into sh_w
// (XOR-(slot&31) column swizzle, 2-way conflict max). No MFMA, no exp/cos.
// Phase 3: as R3 — batch-16 xsv gather, register accumulation, LDS-acc flush,
// write-out with plain stores (only first/last node of the range can be shared).
__global__ __launch_bounds__(256, 3) void msg_kernel(
    const float* __restrict__ vec_csr, const int* __restrict__ slot_dst,
    const int* __restrict__ off, const int* __restrict__ cnt,
    const unsigned* __restrict__ tab,
    const float* __restrict__ xsv,
    float* __restrict__ agg_s, float* __restrict__ agg_v, int E) {
    __shared__ __align__(16) float sh_vec[128][4];      // y0,y1,y2,src-bits
    __shared__ float sh_len[128];
    __shared__ int   sh_dst[128];
    __shared__ __align__(16) unsigned sh_w[128 * 64];   // 32 KB packed, col-swizzled
    __shared__ __align__(16) float sh_acc[ACC_CAP * 256];  // 8 KB node partials

    int tid = threadIdx.x;
    int e0 = blockIdx.x * 128;

    if (tid < 128) {
        int e = e0 + tid;
        float ex = 0.f, ey = 0.f, ez = 0.f, srcb = 0.f;
        int dst = -1;
        if (e < E) {
            float4 vv = *(const float4*)(vec_csr + (size_t)e * 4);
            ex = vv.x; ey = vv.y; ez = vv.z; srcb = vv.w;
            dst = slot_dst[e];
        }
        float len = sqrtf(ex * ex + ey * ey + ez * ez);
        float rinv = SQRT3_F / (len + 1e-9f);
        sh_vec[tid][0] = ex * rinv;
        sh_vec[tid][1] = ey * rinv;
        sh_vec[tid][2] = ez * rinv;
        sh_vec[tid][3] = srcb;
        sh_len[tid] = len;
        sh_dst[tid] = dst;
    }
#pragma unroll
    for (int i = tid; i < ACC_CAP * 64; i += 256)
        ((float4*)sh_acc)[i] = float4{0.f, 0.f, 0.f, 0.f};
    __syncthreads();

    int qw = tid >> 5;      // 0..7, each owns 16 contiguous slots in phase 3
    int u  = tid & 31;
    int base3 = qw * 16;

    // issue the phase-3 xsv gather (16 rows) early; table work gives cover
    float4 x4v[16];
#pragma unroll
    for (int k = 0; k < 16; k++) {
        int src = __float_as_int(sh_vec[base3 + k][3]);
        x4v[k] = *(const float4*)(xsv + (size_t)src * 128 + u * 4);
    }

    {   // ---- phase A: sh_w[slot][col^] = lerp(tab[i], tab[i+1]) at len(slot)
        int slot = tid >> 1;
        int colbase = (tid & 1) << 5;       // 0 or 32
        int sw = slot & 31;
        float len = fminf(sh_len[slot], 3.99995f);
        float t = len * 128.0f;
        int ti = (int)t;
        float frac = t - (float)ti;
        const uint4* pa = (const uint4*)(tab + ti * 64 + colbase);
        unsigned* wrow = sh_w + slot * 64 + colbase;
#pragma unroll
        for (int k = 0; k < 8; k++) {
            uint4 a = pa[k];
            uint4 b = pa[k + 16];           // +64 dwords = next table row
            unsigned av[4] = {a.x, a.y, a.z, a.w};
            unsigned bv[4] = {b.x, b.y, b.z, b.w};
#pragma unroll
            for (int d = 0; d < 4; d++) {
                float la = __uint_as_float(av[d] << 16);
                float ha = __uint_as_float(av[d] & 0xFFFF0000u);
                float lb = __uint_as_float(bv[d] << 16);
                float hb = __uint_as_float(bv[d] & 0xFFFF0000u);
                float ql = la + frac * (lb - la);
                float qh = ha + frac * (hb - ha);
                unsigned r;
                asm("v_cvt_pk_bf16_f32 %0, %1, %2" : "=v"(r) : "v"(ql), "v"(qh));
                int cc = k * 4 + d;
                wrow[cc ^ sw] = r;
            }
        }
    }
    __syncthreads();

    {   // ---- phase 3: messages + hierarchical segmented reduction
        int last = E - 1 - e0; if (last > 127) last = 127;
        int n_first = sh_dst[0];
        int n_last  = sh_dst[last];
        int range = n_last - n_first + 1;
        bool fast = (range <= ACC_CAP);

        float as0 = 0, as1 = 0;
        float av00 = 0, av01 = 0, av02 = 0, av10 = 0, av11 = 0, av12 = 0;
        int run = -1;

        auto flush = [&]() {
            if (run >= 0) {
                if (fast) {
                    float* a = sh_acc + (run - n_first) * 256;
                    atomicAdd(&a[u], as0);
                    atomicAdd(&a[32 + u], as1);
                    atomicAdd(&a[64 + u * 3 + 0], av00);
                    atomicAdd(&a[64 + u * 3 + 1], av01);
                    atomicAdd(&a[64 + u * 3 + 2], av02);
                    atomicAdd(&a[160 + u * 3 + 0], av10);
                    atomicAdd(&a[160 + u * 3 + 1], av11);
                    atomicAdd(&a[160 + u * 3 + 2], av12);
                } else {
                    atomicAdd(&agg_s[run * 64 + u],       as0 * INV_SQRTNN_F);
                    atomicAdd(&agg_s[run * 64 + 32 + u],  as1 * INV_SQRTNN_F);
                    float* av = agg_v + (size_t)run * 192;
                    atomicAdd(&av[u * 3 + 0],      av00 * INV_SQRTNN_F);
                    atomicAdd(&av[u * 3 + 1],      av01 * INV_SQRTNN_F);
                    atomicAdd(&av[u * 3 + 2],      av02 * INV_SQRTNN_F);
                    atomicAdd(&av[96 + u * 3 + 0], av10 * INV_SQRTNN_F);
                    atomicAdd(&av[96 + u * 3 + 1], av11 * INV_SQRTNN_F);
                    atomicAdd(&av[96 + u * 3 + 2], av12 * INV_SQRTNN_F);
                }
            }
            as0 = as1 = av00 = av01 = av02 = av10 = av11 = av12 = 0.f;
        };

#pragma unroll
        for (int k = 0; k < 16; k++) {
            int i = base3 + k;
            int dst = sh_dst[i];
            if (dst != run) { flush(); run = dst; }
            float y0 = sh_vec[i][0], y1 = sh_vec[i][1], y2 = sh_vec[i][2];
            int xu = u ^ (i & 31);
            unsigned q0 = sh_w[i * 64 + xu];
            unsigned q1 = sh_w[i * 64 + 32 + xu];
            float wa = bf2f((unsigned short)q0), wc = bf2f((unsigned short)(q0 >> 16));
            float wb = bf2f((unsigned short)q1), wd = bf2f((unsigned short)(q1 >> 16));
            float4 x4 = x4v[k];
            as0 += wa * x4.w;
            as1 += wb * (y0 * x4.x + y1 * x4.y + y2 * x4.z) * INV_SQRT3_F;
            float tt = wc * x4.w;
            av00 += tt * y0;  av01 += tt * y1;  av02 += tt * y2;
            av10 += wd * x4.x; av11 += wd * x4.y; av12 += wd * x4.z;
        }
        flush();
        __syncthreads();

        if (fast) {
            // only the first/last node of the block's range can have slots
            // outside this window -> interior nodes get plain stores.
            bool leftsh  = off[n_first] < e0;
            bool rightsh = off[n_last] + cnt[n_last] > e0 + 128;
            for (int li = 0; li < range; li++) {
                int n = n_first + li;
                bool shared_node = (li == 0 && leftsh) || (li == range - 1 && rightsh);
                float val = sh_acc[li * 256 + tid] * INV_SQRTNN_F;
                if (tid < 64) {
                    float* dp = &agg_s[n * 64 + tid];
                    if (shared_node) atomicAdd(dp, val); else *dp = val;
                } else {
                    float* dp = &agg_v[(size_t)n * 192 + (tid - 64)];
                    if (shared_node) atomicAdd(dp, val); else *dp = val;
                }
            }
        }
    }
}

// ------------------------------- node update (layer l) + fctp (layer l+1)
__global__ __launch_bounds__(256, 4) void update_fctp(
    const float* __restrict__ agg_s, const float* __restrict__ agg_v,
    const float* __restrict__ attr, const unsigned* __restrict__ Wupk,
    float* __restrict__ sc_s, float* __restrict__ sc_v,
    float* __restrict__ s, float* __restrict__ v,
    const float* __restrict__ Wfp_next, float* __restrict__ xsv,
    int N, int do_fctp) {
    __shared__ __align__(16) char smem[40960];
    node_update_body(blockIdx.x, agg_s, agg_v, attr, Wupk, sc_s, sc_v, s, v, N, smem);
    if (do_fctp) {
        __syncthreads();   // pk/sh_as reads done; s,v global writes drained
        node_fctp_body(blockIdx.x, 0, s, v, attr, Wfp_next, sc_s, sc_v, xsv, N, smem);
        __syncthreads();   // w0/w1 reads done before path-1 reload
        node_fctp_body(blockIdx.x, 1, s, v, attr, Wfp_next, sc_s, sc_v, xsv, N, smem);
    }
}

// ---------------------------------------------------------------- readout
__global__ __launch_bounds__(256) void readout(
    const float* __restrict__ s, const float* __restrict__ attr,
    const float* __restrict__ Wread, const int* __restrict__ batch,
    float* __restrict__ out, int N, float pool_scale) {
    __shared__ float wr[2048];
    __shared__ float red[NGRAPH * 16];
    for (int i = threadIdx.x; i < 2048; i += 256) wr[i] = Wread[i];
    if (threadIdx.x < NGRAPH * 16) red[threadIdx.x] = 0.f;
    __syncthreads();
    int ln = threadIdx.x >> 4, w = threadIdx.x & 15;
    for (int g = 0; g < 4; g++) {
        int n = blockIdx.x * 64 + g * 16 + ln;
        if (n < N) {
            float4 at = *(const float4*)(attr + n * 4);
            float fa[4] = {at.x, at.y, at.z, at.w};
            float acc = 0.f;
            for (int u = 0; u < 32; u++) {
                float su = s[n * 32 + u];
                int base = u * 64 + w;
#pragma unroll
                for (int a = 0; a < 4; a++) acc += su * fa[a] * wr[base + a * 16];
            }
            atomicAdd(&red[batch[n] * 16 + w], acc);
        }
    }
    __syncthreads();
    if (threadIdx.x < NGRAPH * 16) {
        float val = red[threadIdx.x];
        if (val != 0.f)
            atomicAdd(&out[threadIdx.x], val * NORM128_F * pool_scale);
    }
}

// ---------------------------------------------------------------- launch
extern "C" void kernel_launch(void* const* d_in, const int* in_sizes, int n_in,
                              void* d_out, int out_size, void* d_ws, size_t ws_size,
                              hipStream_t stream) {
    const float* x        = (const float*)d_in[0];
    const float* nattr    = (const float*)d_in[1];
    const float* edge_vec = (const float*)d_in[2];
    const int*   batch    = (const int*)d_in[3];
    const int*   esrc     = (const int*)d_in[4];
    const int*   edst     = (const int*)d_in[5];
    const float* Wsc0  = (const float*)d_in[6];
    const float* Wsc1  = (const float*)d_in[7];
    const float* Wl10  = (const float*)d_in[8];
    const float* Wl11  = (const float*)d_in[9];
    const float* Wfc1  = (const float*)d_in[10];
    const float* Wfc2  = (const float*)d_in[11];
    const float* Wl20  = (const float*)d_in[12];
    const float* Wl21  = (const float*)d_in[13];
    const float* Wread = (const float*)d_in[14];

    int N = in_sizes[0] / (MUL * 4);
    int E = in_sizes[2] / 3;

    float* p = (float*)d_ws;
    float* vec_csr = p; p += (size_t)E * 4;     // {ex,ey,ez,src-bits}
    int* slot_dst = (int*)p; p += E;            // dst per CSR slot
    unsigned* tab = (unsigned*)p; p += 2 * NT * 64;  // w(len) tables, packed bf16
    float* Wfp    = p; p += 32768;              // 2 layers x 4 matrices x 4096
    unsigned* Wupk = (unsigned*)p; p += 16384;  // 2 layers x 8192 packed pair dwords
    float* s_buf  = p; p += (size_t)N * 32;
    float* v_buf  = p; p += (size_t)N * 96;
    float* sc_s   = p; p += (size_t)N * 32;
    float* sc_v   = p; p += (size_t)N * 96;
    float* xsv    = p; p += (size_t)N * 128;    // {xv0,xv1,xv2,xs} per (n,u)
    float* aggA_s = p; p += (size_t)N * 64;     // ping-pong agg buffers, contiguous
    float* aggA_v = p; p += (size_t)N * 192;
    float* aggB_s = p; p += (size_t)N * 64;
    float* aggB_v = p; p += (size_t)N * 192;
    int* cnt     = (int*)p; p += N;
    int* off     = (int*)p; p += N;
    int* cursor  = (int*)p; p += N;

    hipMemsetAsync(d_out, 0, (size_t)out_size * sizeof(float), stream);
    hipMemsetAsync(cnt, 0, (size_t)N * sizeof(int), stream);

    int nInit  = (N * 128 + 255) / 256;
    int nSetup = 192;
    int nCount = (E + 255) / 256;
    int nTab   = (2 * NT * 8 + 255) / 256;
    mega1<<<nInit + nSetup + nCount + nTab, 256, 0, stream>>>(
        nInit, nSetup, nCount, x, s_buf, v_buf,
        Wfc1, Wfc2, Wsc0, Wl10, Wsc1, Wl11, Wl20, Wl21,
        Wfp, Wupk, tab, edst, cnt, N, E);

    csr_scan<<<1, 256, 0, stream>>>(cnt, off, cursor, N);

    int nFill = (E + 255) / 256;
    int nF = (N + 15) / 16;
    int nZeroF4 = N * 128;                      // 2 x N*256 floats as float4
    int nZeroBlk = (nZeroF4 + 255) / 256;
    mega2<<<nFill + 2 * nF + nZeroBlk, 256, 0, stream>>>(
        nFill, nF, edst, esrc, edge_vec, cursor, vec_csr, slot_dst, E,
        s_buf, v_buf, nattr, Wfp, sc_s, sc_v, xsv, N, aggA_s, nZeroF4);

    int nE = (E + 127) / 128;

    // ---- layer 0
    msg_kernel<<<nE, 256, 0, stream>>>(
        vec_csr, slot_dst, off, cnt, tab, xsv, aggA_s, aggA_v, E);
    update_fctp<<<nF, 256, 0, stream>>>(
        aggA_s, aggA_v, nattr, Wupk, sc_s, sc_v, s_buf, v_buf,
        Wfp + 16384, xsv, N, 1);

    // ---- layer 1
    msg_kernel<<<nE, 256, 0, stream>>>(
        vec_csr, slot_dst, off, cnt, tab + NT * 64, xsv, aggB_s, aggB_v, E);
    update_fctp<<<nF, 256, 0, stream>>>(
        aggB_s, aggB_v, nattr, Wupk + 8192, sc_s, sc_v, s_buf, v_buf,
        (const float*)0, xsv, N, 0);

    float pool_scale = (float)(1.0 / sqrt((double)N / (double)NGRAPH));
    readout<<<(N + 63) / 64, 256, 0, stream>>>(
        s_buf, nattr, Wread, batch, (float*)d_out, N, pool_scale);
}

// Round 8
// 388.472 us; speedup vs baseline: 1.0124x; 1.0124x over previous
//
#include <hip/hip_runtime.h>
#include <math.h>

#define MUL 32
#define NATTR 4
#define NBASIS 10
#define HID 64
#define OUT_DIM 16
#define NGRAPH 8
#define NT 513      // w(len) table entries: len = i/128, i in [0,512]

#define PI_F 3.14159265358979323846f
#define SQRT3_F 1.7320508075688772f
#define INV_SQRT3_F 0.5773502691896258f
#define INV_SQRT10_F 0.31622776601683794f
#define INV_SQRTNN_F 0.17677669529663687f   // 1/sqrt(32)
#define NORM128_F 0.08838834764831845f      // 1/sqrt(128)
#define NORM256_F 0.0625f                   // 1/sqrt(256)
#define C_S_F 0.3826834323650898f           // sin(pi/8)
#define C_X_F 0.9238795325112867f           // cos(pi/8)
#define CSTEP_F (4.0f/9.0f)                 // linspace(0,4,10) step

#define ACC_CAP 8   // LDS accumulator: max node range per 128-slot block (fast path)

typedef __attribute__((ext_vector_type(4))) float f32x4;
typedef __attribute__((ext_vector_type(4))) unsigned u32x4;

__device__ inline unsigned short f2bf(float x) {
    unsigned u = __float_as_uint(x);
    u += 0x7FFF + ((u >> 16) & 1);          // round-to-nearest-even
    return (unsigned short)(u >> 16);
}
__device__ inline float bf2f(unsigned short h) {
    return __uint_as_float(((unsigned)h) << 16);
}

// ---------------------------------------------------------------- bodies
__device__ __forceinline__ void init_sv_body(
    int blk, const float* __restrict__ x,
    float* __restrict__ s, float* __restrict__ v, int N) {
    int i = blk * 256 + threadIdx.x;
    if (i >= N * 128) return;
    int n = i >> 7, c = i & 127;
    float val = x[i];
    if (c < 32) s[n * 32 + c] = val;
    else        v[n * 96 + (c - 32)] = val;
}

__device__ __forceinline__ void setup_weights_body(
    int blk,
    const float* __restrict__ Wsc0, const float* __restrict__ Wl10,
    const float* __restrict__ Wsc1, const float* __restrict__ Wl11,
    const float* __restrict__ Wl20, const float* __restrict__ Wl21,
    float* __restrict__ Wfp, unsigned* __restrict__ Wupk) {
    int i = blk * 256 + threadIdx.x;
    if (i < 32768) {
        int idx = i >> 12;          // l*4 + m
        int r = i & 4095;
        int l = idx >> 2, m = idx & 3;
        const float* base = (m == 0 ? Wsc0 : m == 1 ? Wl10 : m == 2 ? Wsc1 : Wl11)
                            + l * 4096;
        int u = r >> 7, rr = r & 127, a = rr >> 5, ww = rr & 31;
        Wfp[idx * 4096 + u * 128 + ww * 4 + a] = base[r];
    } else if (i < 49152) {
        int j = i - 32768;
        int l = j >> 13;
        int r = j & 8191;
        int u = r >> 7, rr = r & 127, a = rr >> 5, ww = rr & 31;
        unsigned lo = f2bf(Wl20[l * 8192 + r]);
        unsigned hi = f2bf(Wl21[l * 8192 + r]);
        Wupk[l * 8192 + u * 128 + ww * 4 + a] = lo | (hi << 16);
    }
}

// w(len) table generator: tab[l][i][j] = pack(w_flat[j], w_flat[64+j]) at len=i/128
__device__ __forceinline__ void tab_gen_body(
    int blk, const float* __restrict__ Wfc1, const float* __restrict__ Wfc2,
    unsigned* __restrict__ tab) {
    int id = blk * 256 + threadIdx.x;
    if (id >= 2 * NT * 8) return;
    int l = id / (NT * 8);
    int r = id % (NT * 8);
    int i = r >> 3, cg = r & 7;
    float len = (float)i * (1.0f / 128.0f);
    float uu = len * 0.5f - 2.0f;
    float cut = (uu > 0.0f) ? 0.0f
              : ((uu < -1.0f) ? 1.0f : 0.5f * (1.0f - __cosf(PI_F * uu)));
    float emb[10];
#pragma unroll
    for (int k = 0; k < 10; k++) {
        float d = (len - k * CSTEP_F) * 2.5f;
        emb[k] = __expf(-d * d) * cut;
    }
    float h[64];
    const float* W1 = Wfc1 + l * 640;
#pragma unroll
    for (int n = 0; n < 64; n++) {
        float a = 0.f;
#pragma unroll
        for (int k = 0; k < 10; k++) a += emb[k] * W1[k * 64 + n];
        a *= INV_SQRT10_F;
        h[n] = a / (1.0f + __expf(-a));
    }
    const float* W2 = Wfc2 + l * 8192;
    unsigned* trow = tab + (size_t)l * NT * 64 + i * 64;
    for (int jj = 0; jj < 8; jj++) {
        int j = cg * 8 + jj;
        float w0 = 0.f, w1 = 0.f;
#pragma unroll
        for (int n = 0; n < 64; n++) {
            float hn = h[n];
            w0 += hn * W2[n * 128 + j];
            w1 += hn * W2[n * 128 + 64 + j];
        }
        w0 *= 0.125f; w1 *= 0.125f;
        trow[j] = (unsigned)f2bf(w0) | ((unsigned)f2bf(w1) << 16);
    }
}

__device__ __forceinline__ void csr_count_body(
    int blk, const int* __restrict__ edst, int* __restrict__ cnt, int E) {
    int e = blk * 256 + threadIdx.x;
    if (e < E) atomicAdd(&cnt[edst[e]], 1);
}

__device__ __forceinline__ void csr_fill_body(
    int blk, const int* __restrict__ edst, const int* __restrict__ esrc,
    const float* __restrict__ edge_vec, int* __restrict__ cursor,
    float* __restrict__ vec_csr, int* __restrict__ slot_dst, int E) {
    int e = blk * 256 + threadIdx.x;
    if (e < E) {
        int d = edst[e];
        int p = atomicAdd(&cursor[d], 1);
        float4 vv = {edge_vec[e * 3 + 0], edge_vec[e * 3 + 1], edge_vec[e * 3 + 2],
                     __int_as_float(esrc[e])};
        *(float4*)(vec_csr + (size_t)p * 4) = vv;
        slot_dst[p] = d;
    }
}

// node fctp: 16 nodes/block; smem: [0,16K) w0 | [16K,32K) w1 | [32K,35K) sh
__device__ __forceinline__ void node_fctp_body(
    int blk, int path,
    const float* __restrict__ s, const float* __restrict__ v,
    const float* __restrict__ attr, const float* __restrict__ Wfp,
    float* __restrict__ sc_s, float* __restrict__ sc_v,
    float* __restrict__ xsv, int N, char* smem) {
    float* w0 = (float*)smem;
    float* w1 = (float*)(smem + 16384);
    float (*sh)[96] = (float(*)[96])(smem + 32768);
    int ln = threadIdx.x >> 5, w = threadIdx.x & 31;
    const float4* W0p = (const float4*)(Wfp + path * 8192);
    const float4* W1p = (const float4*)(Wfp + path * 8192 + 4096);
    for (int i = threadIdx.x; i < 1024; i += 256) {
        ((float4*)w0)[i] = W0p[i];
        ((float4*)w1)[i] = W1p[i];
    }
    for (int g = 0; g < 2; g++) {
        int n = blk * 16 + g * 8 + ln;
        bool valid = n < N;
        __syncthreads();
        if (valid) {
            if (path == 0) {
                sh[ln][w] = s[n * 32 + w];
            } else {
                sh[ln][w * 3 + 0] = v[n * 96 + w * 3 + 0];
                sh[ln][w * 3 + 1] = v[n * 96 + w * 3 + 1];
                sh[ln][w * 3 + 2] = v[n * 96 + w * 3 + 2];
            }
        }
        __syncthreads();
        if (!valid) continue;
        float4 at = *(const float4*)(attr + n * 4);
        if (path == 0) {
            float acc0 = 0.f, acc1 = 0.f;
            for (int u = 0; u < 32; u++) {
                float su = sh[ln][u];
                float4 W0v = *(const float4*)(w0 + u * 128 + w * 4);
                float4 W1v = *(const float4*)(w1 + u * 128 + w * 4);
                float d0 = at.x * W0v.x + at.y * W0v.y + at.z * W0v.z + at.w * W0v.w;
                float d1 = at.x * W1v.x + at.y * W1v.y + at.z * W1v.z + at.w * W1v.w;
                acc0 += su * d0;
                acc1 += su * d1;
            }
            sc_s[n * 32 + w] = acc0 * NORM128_F;
            xsv[(size_t)n * 128 + w * 4 + 3] = acc1 * NORM128_F;
        } else {
            float a00 = 0, a01 = 0, a02 = 0, a10 = 0, a11 = 0, a12 = 0;
            for (int u = 0; u < 32; u++) {
                float vu0 = sh[ln][u * 3 + 0];
                float vu1 = sh[ln][u * 3 + 1];
                float vu2 = sh[ln][u * 3 + 2];
                float4 W0v = *(const float4*)(w0 + u * 128 + w * 4);
                float4 W1v = *(const float4*)(w1 + u * 128 + w * 4);
                float d0 = at.x * W0v.x + at.y * W0v.y + at.z * W0v.z + at.w * W0v.w;
                float d1 = at.x * W1v.x + at.y * W1v.y + at.z * W1v.z + at.w * W1v.w;
                a00 += vu0 * d0; a01 += vu1 * d0; a02 += vu2 * d0;
                a10 += vu0 * d1; a11 += vu1 * d1; a12 += vu2 * d1;
            }
            sc_v[n * 96 + w * 3 + 0] = a00 * NORM128_F;
            sc_v[n * 96 + w * 3 + 1] = a01 * NORM128_F;
            sc_v[n * 96 + w * 3 + 2] = a02 * NORM128_F;
            float* xp = xsv + (size_t)n * 128 + w * 4;
            xp[0] = a10 * NORM128_F;
            xp[1] = a11 * NORM128_F;
            xp[2] = a12 * NORM128_F;
        }
    }
}

// node update: smem [0,32K) pk | [32K,34K) sh_as | [34K,40K) sh_av
__device__ __forceinline__ void node_update_body(
    int blk, const float* __restrict__ agg_s, const float* __restrict__ agg_v,
    const float* __restrict__ attr, const unsigned* __restrict__ Wupk,
    const float* __restrict__ sc_s, const float* __restrict__ sc_v,
    float* __restrict__ s, float* __restrict__ v, int N, char* smem) {
    unsigned* pk = (unsigned*)smem;
    float (*sh_as)[64]  = (float(*)[64])(smem + 32768);
    float (*sh_av)[192] = (float(*)[192])(smem + 32768 + 2048);
    int ln = threadIdx.x >> 5, w = threadIdx.x & 31;
    for (int i = threadIdx.x; i < 2048; i += 256)
        ((uint4*)pk)[i] = ((const uint4*)Wupk)[i];
    for (int g = 0; g < 2; g++) {
        int n = blk * 16 + g * 8 + ln;
        bool valid = n < N;
        __syncthreads();
        if (valid) {
            sh_as[ln][w] = agg_s[n * 64 + w];
            sh_as[ln][32 + w] = agg_s[n * 64 + 32 + w];
#pragma unroll
            for (int i = 0; i < 6; i++)
                sh_av[ln][w * 6 + i] = agg_v[(size_t)n * 192 + w * 6 + i];
        }
        __syncthreads();
        if (!valid) continue;
        float4 at = *(const float4*)(attr + n * 4);
        float acc_s = 0.f, a0 = 0.f, a1 = 0.f, a2 = 0.f;
        for (int u = 0; u < 64; u++) {
            float gs = sh_as[ln][u];
            float g0 = sh_av[ln][u * 3 + 0];
            float g1 = sh_av[ln][u * 3 + 1];
            float g2 = sh_av[ln][u * 3 + 2];
            uint4 pv = *(const uint4*)(pk + u * 128 + w * 4);
            float w20x = bf2f((unsigned short)pv.x), w21x = bf2f((unsigned short)(pv.x >> 16));
            float w20y = bf2f((unsigned short)pv.y), w21y = bf2f((unsigned short)(pv.y >> 16));
            float w20z = bf2f((unsigned short)pv.z), w21z = bf2f((unsigned short)(pv.z >> 16));
            float w20w = bf2f((unsigned short)pv.w), w21w = bf2f((unsigned short)(pv.w >> 16));
            float d0 = at.x * w20x + at.y * w20y + at.z * w20z + at.w * w20w;
            float d1 = at.x * w21x + at.y * w21y + at.z * w21z + at.w * w21w;
            acc_s += gs * d0;
            a0 += g0 * d1; a1 += g1 * d1; a2 += g2 * d1;
        }
        float os = acc_s * NORM256_F;
        float sn = C_S_F * sc_s[n * 32 + w] + C_X_F * os;
        float sig = 1.0f / (1.0f + __expf(-sn));
        s[n * 32 + w] += sn * sig;   // silu(sn)
        float ov0 = a0 * NORM256_F, ov1 = a1 * NORM256_F, ov2 = a2 * NORM256_F;
        v[n * 96 + w * 3 + 0] += (C_S_F * sc_v[n * 96 + w * 3 + 0] + C_X_F * ov0) * sig;
        v[n * 96 + w * 3 + 1] += (C_S_F * sc_v[n * 96 + w * 3 + 1] + C_X_F * ov1) * sig;
        v[n * 96 + w * 3 + 2] += (C_S_F * sc_v[n * 96 + w * 3 + 2] + C_X_F * ov2) * sig;
    }
}

// ---------------------------------------------------------------- mega kernels
__global__ __launch_bounds__(256) void mega1(
    int nInit, int nSetup, int nCount,
    const float* __restrict__ x, float* __restrict__ s, float* __restrict__ v,
    const float* __restrict__ Wfc1, const float* __restrict__ Wfc2,
    const float* __restrict__ Wsc0, const float* __restrict__ Wl10,
    const float* __restrict__ Wsc1, const float* __restrict__ Wl11,
    const float* __restrict__ Wl20, const float* __restrict__ Wl21,
    float* __restrict__ Wfp, unsigned* __restrict__ Wupk,
    unsigned* __restrict__ tab,
    const int* __restrict__ edst, int* __restrict__ cnt, int N, int E) {
    int b = blockIdx.x;
    if (b < nInit) { init_sv_body(b, x, s, v, N); return; }
    b -= nInit;
    if (b < nSetup) {
        setup_weights_body(b, Wsc0, Wl10, Wsc1, Wl11, Wl20, Wl21, Wfp, Wupk);
        return;
    }
    b -= nSetup;
    if (b < nCount) { csr_count_body(b, edst, cnt, E); return; }
    b -= nCount;
    tab_gen_body(b, Wfc1, Wfc2, tab);
}

__global__ void csr_scan(const int* __restrict__ cnt, int* __restrict__ off,
                         int* __restrict__ cursor, int N) {
    __shared__ int sums[256];
    int t = threadIdx.x;
    int chunk = (N + 255) / 256;
    int lo = t * chunk, hi = lo + chunk; if (hi > N) hi = N;
    int s = 0;
    for (int i = lo; i < hi; i++) s += cnt[i];
    sums[t] = s;
    __syncthreads();
    for (int d = 1; d < 256; d <<= 1) {
        int v = (t >= d) ? sums[t - d] : 0;
        __syncthreads();
        sums[t] += v;
        __syncthreads();
    }
    int run = (t == 0) ? 0 : sums[t - 1];
    for (int i = lo; i < hi; i++) {
        off[i] = run; cursor[i] = run;
        run += cnt[i];
    }
}

// csr_fill || fctp(layer0, both paths) || zero agg ping-pong buffers
__global__ __launch_bounds__(256, 4) void mega2(
    int nFill, int nF,
    const int* __restrict__ edst, const int* __restrict__ esrc,
    const float* __restrict__ edge_vec, int* __restrict__ cursor,
    float* __restrict__ vec_csr, int* __restrict__ slot_dst, int E,
    const float* __restrict__ s, const float* __restrict__ v,
    const float* __restrict__ attr, const float* __restrict__ Wfp,
    float* __restrict__ sc_s, float* __restrict__ sc_v,
    float* __restrict__ xsv, int N,
    float* __restrict__ zero_base, int nZeroF4) {
    __shared__ __align__(16) char smem[35840];
    int b = blockIdx.x;
    if (b < nFill) {
        csr_fill_body(b, edst, esrc, edge_vec, cursor, vec_csr, slot_dst, E);
        return;
    }
    b -= nFill;
    if (b < 2 * nF) {
        node_fctp_body(b % nF, b / nF, s, v, attr, Wfp, sc_s, sc_v, xsv, N, smem);
        return;
    }
    b -= 2 * nF;
    int i = b * 256 + threadIdx.x;
    if (i < nZeroF4) {
        float4 z = {0.f, 0.f, 0.f, 0.f};
        ((float4*)zero_base)[i] = z;
    }
}

// ---------------------------------------------------------------- msg kernel
// Table-driven edge weights + message + hierarchical reduction.
// 128 CSR slots/block.
//  - xsv gather (16 f32x4 rows/thread) issued up front and PINNED via empty
//    inline-asm "v" constraints after the phase-A barrier: forces all 16 loads
//    live and concurrent (16-way MLP) instead of a sunk serial chain.
//  - phase A tab loads likewise batched (8 a-rows + 8 b-rows) and pinned.
// Phase 3: register accumulation, LDS-acc flush, write-out with plain stores
// (only first/last node of a block's range can be shared with neighbors).
__global__ __launch_bounds__(256, 3) void msg_kernel(
    const float* __restrict__ vec_csr, const int* __restrict__ slot_dst,
    const int* __restrict__ off, const int* __restrict__ cnt,
    const unsigned* __restrict__ tab,
    const float* __restrict__ xsv,
    float* __restrict__ agg_s, float* __restrict__ agg_v, int E) {
    __shared__ __align__(16) float sh_vec[128][4];      // y0,y1,y2,src-bits
    __shared__ float sh_len[128];
    __shared__ int   sh_dst[128];
    __shared__ __align__(16) unsigned sh_w[128 * 64];   // 32 KB packed, col-swizzled
    __shared__ __align__(16) float sh_acc[ACC_CAP * 256];  // 8 KB node partials

    int tid = threadIdx.x;
    int e0 = blockIdx.x * 128;

    if (tid < 128) {
        int e = e0 + tid;
        float ex = 0.f, ey = 0.f, ez = 0.f, srcb = 0.f;
        int dst = -1;
        if (e < E) {
            float4 vv = *(const float4*)(vec_csr + (size_t)e * 4);
            ex = vv.x; ey = vv.y; ez = vv.z; srcb = vv.w;
            dst = slot_dst[e];
        }
        float len = sqrtf(ex * ex + ey * ey + ez * ez);
        float rinv = SQRT3_F / (len + 1e-9f);
        sh_vec[tid][0] = ex * rinv;
        sh_vec[tid][1] = ey * rinv;
        sh_vec[tid][2] = ez * rinv;
        sh_vec[tid][3] = srcb;
        sh_len[tid] = len;
        sh_dst[tid] = dst;
    }
#pragma unroll
    for (int i = tid; i < ACC_CAP * 64; i += 256)
        ((float4*)sh_acc)[i] = float4{0.f, 0.f, 0.f, 0.f};
    __syncthreads();

    int qw = tid >> 5;      // 0..7, each owns 16 contiguous slots in phase 3
    int u  = tid & 31;
    int base3 = qw * 16;

    // ---- issue the phase-3 xsv gather (16 independent rows) up front
    f32x4 x4v[16];
#pragma unroll
    for (int k = 0; k < 16; k++) {
        int src = __float_as_int(sh_vec[base3 + k][3]);
        x4v[k] = *(const f32x4*)(xsv + (size_t)src * 128 + u * 4);
    }

    {   // ---- phase A: sh_w[slot][col^] = lerp(tab[i], tab[i+1]) at len(slot)
        int slot = tid >> 1;
        int colbase = (tid & 1) << 5;       // 0 or 32
        int sw = slot & 31;
        float len = fminf(sh_len[slot], 3.99995f);
        float t = len * 128.0f;
        int ti = (int)t;
        float frac = t - (float)ti;
        const u32x4* pa = (const u32x4*)(tab + ti * 64 + colbase);
        unsigned* wrow = sh_w + slot * 64 + colbase;
        u32x4 a[8], b[8];
#pragma unroll
        for (int k = 0; k < 8; k++) {
            a[k] = pa[k];
            b[k] = pa[k + 16];              // +64 dwords = next table row
        }
#pragma unroll
        for (int k = 0; k < 8; k++) {       // pin: force concurrent completion
#pragma unroll
            for (int d = 0; d < 4; d++) {
                unsigned ta_ = a[k][d], tb_ = b[k][d];
                asm volatile("" : "+v"(ta_));
                asm volatile("" : "+v"(tb_));
                a[k][d] = ta_; b[k][d] = tb_;
            }
        }
#pragma unroll
        for (int k = 0; k < 8; k++) {
#pragma unroll
            for (int d = 0; d < 4; d++) {
                unsigned av = a[k][d], bv = b[k][d];
                float la = __uint_as_float(av << 16);
                float ha = __uint_as_float(av & 0xFFFF0000u);
                float lb = __uint_as_float(bv << 16);
                float hb = __uint_as_float(bv & 0xFFFF0000u);
                float ql = la + frac * (lb - la);
                float qh = ha + frac * (hb - ha);
                unsigned r;
                asm("v_cvt_pk_bf16_f32 %0, %1, %2" : "=v"(r) : "v"(ql), "v"(qh));
                int cc = k * 4 + d;
                wrow[cc ^ sw] = r;
            }
        }
    }
    __syncthreads();

    // pin the gather AFTER the barrier: all 16 loads must be complete and
    // simultaneously live here -> compiler cannot serialize them into the loop.
#pragma unroll
    for (int k = 0; k < 16; k++) {
#pragma unroll
        for (int d = 0; d < 4; d++) {
            float tv_ = x4v[k][d];
            asm volatile("" : "+v"(tv_));
            x4v[k][d] = tv_;
        }
    }

    {   // ---- phase 3: messages + hierarchical segmented reduction
        int last = E - 1 - e0; if (last > 127) last = 127;
        int n_first = sh_dst[0];
        int n_last  = sh_dst[last];
        int range = n_last - n_first + 1;
        bool fast = (range <= ACC_CAP);

        float as0 = 0, as1 = 0;
        float av00 = 0, av01 = 0, av02 = 0, av10 = 0, av11 = 0, av12 = 0;
        int run = -1;

        auto flush = [&]() {
            if (run >= 0) {
                if (fast) {
                    float* a = sh_acc + (run - n_first) * 256;
                    atomicAdd(&a[u], as0);
                    atomicAdd(&a[32 + u], as1);
                    atomicAdd(&a[64 + u * 3 + 0], av00);
                    atomicAdd(&a[64 + u * 3 + 1], av01);
                    atomicAdd(&a[64 + u * 3 + 2], av02);
                    atomicAdd(&a[160 + u * 3 + 0], av10);
                    atomicAdd(&a[160 + u * 3 + 1], av11);
                    atomicAdd(&a[160 + u * 3 + 2], av12);
                } else {
                    atomicAdd(&agg_s[run * 64 + u],       as0 * INV_SQRTNN_F);
                    atomicAdd(&agg_s[run * 64 + 32 + u],  as1 * INV_SQRTNN_F);
                    float* av = agg_v + (size_t)run * 192;
                    atomicAdd(&av[u * 3 + 0],      av00 * INV_SQRTNN_F);
                    atomicAdd(&av[u * 3 + 1],      av01 * INV_SQRTNN_F);
                    atomicAdd(&av[u * 3 + 2],      av02 * INV_SQRTNN_F);
                    atomicAdd(&av[96 + u * 3 + 0], av10 * INV_SQRTNN_F);
                    atomicAdd(&av[96 + u * 3 + 1], av11 * INV_SQRTNN_F);
                    atomicAdd(&av[96 + u * 3 + 2], av12 * INV_SQRTNN_F);
                }
            }
            as0 = as1 = av00 = av01 = av02 = av10 = av11 = av12 = 0.f;
        };

#pragma unroll
        for (int k = 0; k < 16; k++) {
            int i = base3 + k;
            int dst = sh_dst[i];
            if (dst != run) { flush(); run = dst; }
            float y0 = sh_vec[i][0], y1 = sh_vec[i][1], y2 = sh_vec[i][2];
            int xu = u ^ (i & 31);
            unsigned q0 = sh_w[i * 64 + xu];
            unsigned q1 = sh_w[i * 64 + 32 + xu];
            float wa = bf2f((unsigned short)q0), wc = bf2f((unsigned short)(q0 >> 16));
            float wb = bf2f((unsigned short)q1), wd = bf2f((unsigned short)(q1 >> 16));
            f32x4 x4 = x4v[k];
            as0 += wa * x4[3];
            as1 += wb * (y0 * x4[0] + y1 * x4[1] + y2 * x4[2]) * INV_SQRT3_F;
            float tt = wc * x4[3];
            av00 += tt * y0;  av01 += tt * y1;  av02 += tt * y2;
            av10 += wd * x4[0]; av11 += wd * x4[1]; av12 += wd * x4[2];
        }
        flush();
        __syncthreads();

        if (fast) {
            // only the first/last node of the block's range can have slots
            // outside this window -> interior nodes get plain stores.
            bool leftsh  = off[n_first] < e0;
            bool rightsh = off[n_last] + cnt[n_last] > e0 + 128;
            for (int li = 0; li < range; li++) {
                int n = n_first + li;
                bool shared_node = (li == 0 && leftsh) || (li == range - 1 && rightsh);
                float val = sh_acc[li * 256 + tid] * INV_SQRTNN_F;
                if (tid < 64) {
                    float* dp = &agg_s[n * 64 + tid];
                    if (shared_node) atomicAdd(dp, val); else *dp = val;
                } else {
                    float* dp = &agg_v[(size_t)n * 192 + (tid - 64)];
                    if (shared_node) atomicAdd(dp, val); else *dp = val;
                }
            }
        }
    }
}

// ------------------------------- node update (layer l) + fctp (layer l+1)
__global__ __launch_bounds__(256, 4) void update_fctp(
    const float* __restrict__ agg_s, const float* __restrict__ agg_v,
    const float* __restrict__ attr, const unsigned* __restrict__ Wupk,
    float* __restrict__ sc_s, float* __restrict__ sc_v,
    float* __restrict__ s, float* __restrict__ v,
    const float* __restrict__ Wfp_next, float* __restrict__ xsv,
    int N, int do_fctp) {
    __shared__ __align__(16) char smem[40960];
    node_update_body(blockIdx.x, agg_s, agg_v, attr, Wupk, sc_s, sc_v, s, v, N, smem);
    if (do_fctp) {
        __syncthreads();   // pk/sh_as reads done; s,v global writes drained
        node_fctp_body(blockIdx.x, 0, s, v, attr, Wfp_next, sc_s, sc_v, xsv, N, smem);
        __syncthreads();   // w0/w1 reads done before path-1 reload
        node_fctp_body(blockIdx.x, 1, s, v, attr, Wfp_next, sc_s, sc_v, xsv, N, smem);
    }
}

// ---------------------------------------------------------------- readout
__global__ __launch_bounds__(256) void readout(
    const float* __restrict__ s, const float* __restrict__ attr,
    const float* __restrict__ Wread, const int* __restrict__ batch,
    float* __restrict__ out, int N, float pool_scale) {
    __shared__ float wr[2048];
    __shared__ float red[NGRAPH * 16];
    for (int i = threadIdx.x; i < 2048; i += 256) wr[i] = Wread[i];
    if (threadIdx.x < NGRAPH * 16) red[threadIdx.x] = 0.f;
    __syncthreads();
    int ln = threadIdx.x >> 4, w = threadIdx.x & 15;
    for (int g = 0; g < 4; g++) {
        int n = blockIdx.x * 64 + g * 16 + ln;
        if (n < N) {
            float4 at = *(const float4*)(attr + n * 4);
            float fa[4] = {at.x, at.y, at.z, at.w};
            float acc = 0.f;
            for (int u = 0; u < 32; u++) {
                float su = s[n * 32 + u];
                int base = u * 64 + w;
#pragma unroll
                for (int a = 0; a < 4; a++) acc += su * fa[a] * wr[base + a * 16];
            }
            atomicAdd(&red[batch[n] * 16 + w], acc);
        }
    }
    __syncthreads();
    if (threadIdx.x < NGRAPH * 16) {
        float val = red[threadIdx.x];
        if (val != 0.f)
            atomicAdd(&out[threadIdx.x], val * NORM128_F * pool_scale);
    }
}

// ---------------------------------------------------------------- launch
extern "C" void kernel_launch(void* const* d_in, const int* in_sizes, int n_in,
                              void* d_out, int out_size, void* d_ws, size_t ws_size,
                              hipStream_t stream) {
    const float* x        = (const float*)d_in[0];
    const float* nattr    = (const float*)d_in[1];
    const float* edge_vec = (const float*)d_in[2];
    const int*   batch    = (const int*)d_in[3];
    const int*   esrc     = (const int*)d_in[4];
    const int*   edst     = (const int*)d_in[5];
    const float* Wsc0  = (const float*)d_in[6];
    const float* Wsc1  = (const float*)d_in[7];
    const float* Wl10  = (const float*)d_in[8];
    const float* Wl11  = (const float*)d_in[9];
    const float* Wfc1  = (const float*)d_in[10];
    const float* Wfc2  = (const float*)d_in[11];
    const float* Wl20  = (const float*)d_in[12];
    const float* Wl21  = (const float*)d_in[13];
    const float* Wread = (const float*)d_in[14];

    int N = in_sizes[0] / (MUL * 4);
    int E = in_sizes[2] / 3;

    float* p = (float*)d_ws;
    float* vec_csr = p; p += (size_t)E * 4;     // {ex,ey,ez,src-bits}
    int* slot_dst = (int*)p; p += E;            // dst per CSR slot
    unsigned* tab = (unsigned*)p; p += 2 * NT * 64;  // w(len) tables, packed bf16
    float* Wfp    = p; p += 32768;              // 2 layers x 4 matrices x 4096
    unsigned* Wupk = (unsigned*)p; p += 16384;  // 2 layers x 8192 packed pair dwords
    float* s_buf  = p; p += (size_t)N * 32;
    float* v_buf  = p; p += (size_t)N * 96;
    float* sc_s   = p; p += (size_t)N * 32;
    float* sc_v   = p; p += (size_t)N * 96;
    float* xsv    = p; p += (size_t)N * 128;    // {xv0,xv1,xv2,xs} per (n,u)
    float* aggA_s = p; p += (size_t)N * 64;     // ping-pong agg buffers, contiguous
    float* aggA_v = p; p += (size_t)N * 192;
    float* aggB_s = p; p += (size_t)N * 64;
    float* aggB_v = p; p += (size_t)N * 192;
    int* cnt     = (int*)p; p += N;
    int* off     = (int*)p; p += N;
    int* cursor  = (int*)p; p += N;

    hipMemsetAsync(d_out, 0, (size_t)out_size * sizeof(float), stream);
    hipMemsetAsync(cnt, 0, (size_t)N * sizeof(int), stream);

    int nInit  = (N * 128 + 255) / 256;
    int nSetup = 192;
    int nCount = (E + 255) / 256;
    int nTab   = (2 * NT * 8 + 255) / 256;
    mega1<<<nInit + nSetup + nCount + nTab, 256, 0, stream>>>(
        nInit, nSetup, nCount, x, s_buf, v_buf,
        Wfc1, Wfc2, Wsc0, Wl10, Wsc1, Wl11, Wl20, Wl21,
        Wfp, Wupk, tab, edst, cnt, N, E);

    csr_scan<<<1, 256, 0, stream>>>(cnt, off, cursor, N);

    int nFill = (E + 255) / 256;
    int nF = (N + 15) / 16;
    int nZeroF4 = N * 128;                      // 2 x N*256 floats as float4
    int nZeroBlk = (nZeroF4 + 255) / 256;
    mega2<<<nFill + 2 * nF + nZeroBlk, 256, 0, stream>>>(
        nFill, nF, edst, esrc, edge_vec, cursor, vec_csr, slot_dst, E,
        s_buf, v_buf, nattr, Wfp, sc_s, sc_v, xsv, N, aggA_s, nZeroF4);

    int nE = (E + 127) / 128;

    // ---- layer 0
    msg_kernel<<<nE, 256, 0, stream>>>(
        vec_csr, slot_dst, off, cnt, tab, xsv, aggA_s, aggA_v, E);
    update_fctp<<<nF, 256, 0, stream>>>(
        aggA_s, aggA_v, nattr, Wupk, sc_s, sc_v, s_buf, v_buf,
        Wfp + 16384, xsv, N, 1);

    // ---- layer 1
    msg_kernel<<<nE, 256, 0, stream>>>(
        vec_csr, slot_dst, off, cnt, tab + NT * 64, xsv, aggB_s, aggB_v, E);
    update_fctp<<<nF, 256, 0, stream>>>(
        aggB_s, aggB_v, nattr, Wupk + 8192, sc_s, sc_v, s_buf, v_buf,
        (const float*)0, xsv, N, 0);

    float pool_scale = (float)(1.0 / sqrt((double)N / (double)NGRAPH));
    readout<<<(N + 63) / 64, 256, 0, stream>>>(
        s_buf, nattr, Wread, batch, (float*)d_out, N, pool_scale);
}

// Round 9
// 317.559 us; speedup vs baseline: 1.2384x; 1.2233x over previous
//
#include <hip/hip_runtime.h>
#include <math.h>

#define MUL 32
#define NATTR 4
#define NBASIS 10
#define HID 64
#define OUT_DIM 16
#define NGRAPH 8
#define NT 513      // w(len) table entries: len = i/128, i in [0,512]

#define PI_F 3.14159265358979323846f
#define SQRT3_F 1.7320508075688772f
#define INV_SQRT3_F 0.5773502691896258f
#define INV_SQRT10_F 0.31622776601683794f
#define INV_SQRTNN_F 0.17677669529663687f   // 1/sqrt(32)
#define NORM128_F 0.08838834764831845f      // 1/sqrt(128)
#define NORM256_F 0.0625f                   // 1/sqrt(256)
#define C_S_F 0.3826834323650898f           // sin(pi/8)
#define C_X_F 0.9238795325112867f           // cos(pi/8)
#define CSTEP_F (4.0f/9.0f)                 // linspace(0,4,10) step

__device__ inline unsigned short f2bf(float x) {
    unsigned u = __float_as_uint(x);
    u += 0x7FFF + ((u >> 16) & 1);          // round-to-nearest-even
    return (unsigned short)(u >> 16);
}
__device__ inline float bf2f(unsigned short h) {
    return __uint_as_float(((unsigned)h) << 16);
}

// ---------------------------------------------------------------- bodies
__device__ __forceinline__ void init_sv_body(
    int blk, const float* __restrict__ x,
    float* __restrict__ s, float* __restrict__ v, int N) {
    int i = blk * 256 + threadIdx.x;
    if (i >= N * 128) return;
    int n = i >> 7, c = i & 127;
    float val = x[i];
    if (c < 32) s[n * 32 + c] = val;
    else        v[n * 96 + (c - 32)] = val;
}

__device__ __forceinline__ void setup_weights_body(
    int blk,
    const float* __restrict__ Wsc0, const float* __restrict__ Wl10,
    const float* __restrict__ Wsc1, const float* __restrict__ Wl11,
    const float* __restrict__ Wl20, const float* __restrict__ Wl21,
    float* __restrict__ Wfp, unsigned* __restrict__ Wupk) {
    int i = blk * 256 + threadIdx.x;
    if (i < 32768) {
        int idx = i >> 12;          // l*4 + m
        int r = i & 4095;
        int l = idx >> 2, m = idx & 3;
        const float* base = (m == 0 ? Wsc0 : m == 1 ? Wl10 : m == 2 ? Wsc1 : Wl11)
                            + l * 4096;
        int u = r >> 7, rr = r & 127, a = rr >> 5, ww = rr & 31;
        Wfp[idx * 4096 + u * 128 + ww * 4 + a] = base[r];
    } else if (i < 49152) {
        int j = i - 32768;
        int l = j >> 13;
        int r = j & 8191;
        int u = r >> 7, rr = r & 127, a = rr >> 5, ww = rr & 31;
        unsigned lo = f2bf(Wl20[l * 8192 + r]);
        unsigned hi = f2bf(Wl21[l * 8192 + r]);
        Wupk[l * 8192 + u * 128 + ww * 4 + a] = lo | (hi << 16);
    }
}

// w(len) table generator: tab[l][i][j] = pack(w_flat[j], w_flat[64+j]) at len=i/128
__device__ __forceinline__ void tab_gen_body(
    int blk, const float* __restrict__ Wfc1, const float* __restrict__ Wfc2,
    unsigned* __restrict__ tab) {
    int id = blk * 256 + threadIdx.x;
    if (id >= 2 * NT * 8) return;
    int l = id / (NT * 8);
    int r = id % (NT * 8);
    int i = r >> 3, cg = r & 7;
    float len = (float)i * (1.0f / 128.0f);
    float uu = len * 0.5f - 2.0f;
    float cut = (uu > 0.0f) ? 0.0f
              : ((uu < -1.0f) ? 1.0f : 0.5f * (1.0f - __cosf(PI_F * uu)));
    float emb[10];
#pragma unroll
    for (int k = 0; k < 10; k++) {
        float d = (len - k * CSTEP_F) * 2.5f;
        emb[k] = __expf(-d * d) * cut;
    }
    float h[64];
    const float* W1 = Wfc1 + l * 640;
#pragma unroll
    for (int n = 0; n < 64; n++) {
        float a = 0.f;
#pragma unroll
        for (int k = 0; k < 10; k++) a += emb[k] * W1[k * 64 + n];
        a *= INV_SQRT10_F;
        h[n] = a / (1.0f + __expf(-a));
    }
    const float* W2 = Wfc2 + l * 8192;
    unsigned* trow = tab + (size_t)l * NT * 64 + i * 64;
    for (int jj = 0; jj < 8; jj++) {
        int j = cg * 8 + jj;
        float w0 = 0.f, w1 = 0.f;
#pragma unroll
        for (int n = 0; n < 64; n++) {
            float hn = h[n];
            w0 += hn * W2[n * 128 + j];
            w1 += hn * W2[n * 128 + 64 + j];
        }
        w0 *= 0.125f; w1 *= 0.125f;
        trow[j] = (unsigned)f2bf(w0) | ((unsigned)f2bf(w1) << 16);
    }
}

__device__ __forceinline__ void csr_count_body(
    int blk, const int* __restrict__ edst, int* __restrict__ cnt, int E) {
    int e = blk * 256 + threadIdx.x;
    if (e < E) atomicAdd(&cnt[edst[e]], 1);
}

__device__ __forceinline__ void csr_fill_body(
    int blk, const int* __restrict__ edst, const int* __restrict__ esrc,
    const float* __restrict__ edge_vec, int* __restrict__ cursor,
    float* __restrict__ vec_csr, int E) {
    int e = blk * 256 + threadIdx.x;
    if (e < E) {
        int d = edst[e];
        int p = atomicAdd(&cursor[d], 1);
        float4 vv = {edge_vec[e * 3 + 0], edge_vec[e * 3 + 1], edge_vec[e * 3 + 2],
                     __int_as_float(esrc[e])};
        *(float4*)(vec_csr + (size_t)p * 4) = vv;
    }
}

// node fctp: 16 nodes/block; smem: [0,16K) w0 | [16K,32K) w1 | [32K,35K) sh
__device__ __forceinline__ void node_fctp_body(
    int blk, int path,
    const float* __restrict__ s, const float* __restrict__ v,
    const float* __restrict__ attr, const float* __restrict__ Wfp,
    float* __restrict__ sc_s, float* __restrict__ sc_v,
    float* __restrict__ xsv, int N, char* smem) {
    float* w0 = (float*)smem;
    float* w1 = (float*)(smem + 16384);
    float (*sh)[96] = (float(*)[96])(smem + 32768);
    int ln = threadIdx.x >> 5, w = threadIdx.x & 31;
    const float4* W0p = (const float4*)(Wfp + path * 8192);
    const float4* W1p = (const float4*)(Wfp + path * 8192 + 4096);
    for (int i = threadIdx.x; i < 1024; i += 256) {
        ((float4*)w0)[i] = W0p[i];
        ((float4*)w1)[i] = W1p[i];
    }
    for (int g = 0; g < 2; g++) {
        int n = blk * 16 + g * 8 + ln;
        bool valid = n < N;
        __syncthreads();
        if (valid) {
            if (path == 0) {
                sh[ln][w] = s[n * 32 + w];
            } else {
                sh[ln][w * 3 + 0] = v[n * 96 + w * 3 + 0];
                sh[ln][w * 3 + 1] = v[n * 96 + w * 3 + 1];
                sh[ln][w * 3 + 2] = v[n * 96 + w * 3 + 2];
            }
        }
        __syncthreads();
        if (!valid) continue;
        float4 at = *(const float4*)(attr + n * 4);
        if (path == 0) {
            float acc0 = 0.f, acc1 = 0.f;
            for (int u = 0; u < 32; u++) {
                float su = sh[ln][u];
                float4 W0v = *(const float4*)(w0 + u * 128 + w * 4);
                float4 W1v = *(const float4*)(w1 + u * 128 + w * 4);
                float d0 = at.x * W0v.x + at.y * W0v.y + at.z * W0v.z + at.w * W0v.w;
                float d1 = at.x * W1v.x + at.y * W1v.y + at.z * W1v.z + at.w * W1v.w;
                acc0 += su * d0;
                acc1 += su * d1;
            }
            sc_s[n * 32 + w] = acc0 * NORM128_F;
            xsv[(size_t)n * 128 + w * 4 + 3] = acc1 * NORM128_F;
        } else {
            float a00 = 0, a01 = 0, a02 = 0, a10 = 0, a11 = 0, a12 = 0;
            for (int u = 0; u < 32; u++) {
                float vu0 = sh[ln][u * 3 + 0];
                float vu1 = sh[ln][u * 3 + 1];
                float vu2 = sh[ln][u * 3 + 2];
                float4 W0v = *(const float4*)(w0 + u * 128 + w * 4);
                float4 W1v = *(const float4*)(w1 + u * 128 + w * 4);
                float d0 = at.x * W0v.x + at.y * W0v.y + at.z * W0v.z + at.w * W0v.w;
                float d1 = at.x * W1v.x + at.y * W1v.y + at.z * W1v.z + at.w * W1v.w;
                a00 += vu0 * d0; a01 += vu1 * d0; a02 += vu2 * d0;
                a10 += vu0 * d1; a11 += vu1 * d1; a12 += vu2 * d1;
            }
            sc_v[n * 96 + w * 3 + 0] = a00 * NORM128_F;
            sc_v[n * 96 + w * 3 + 1] = a01 * NORM128_F;
            sc_v[n * 96 + w * 3 + 2] = a02 * NORM128_F;
            float* xp = xsv + (size_t)n * 128 + w * 4;
            xp[0] = a10 * NORM128_F;
            xp[1] = a11 * NORM128_F;
            xp[2] = a12 * NORM128_F;
        }
    }
}

// node update: smem [0,32K) pk | [32K,34K) sh_as | [34K,40K) sh_av
__device__ __forceinline__ void node_update_body(
    int blk, const float* __restrict__ agg_s, const float* __restrict__ agg_v,
    const float* __restrict__ attr, const unsigned* __restrict__ Wupk,
    const float* __restrict__ sc_s, const float* __restrict__ sc_v,
    float* __restrict__ s, float* __restrict__ v, int N, char* smem) {
    unsigned* pk = (unsigned*)smem;
    float (*sh_as)[64]  = (float(*)[64])(smem + 32768);
    float (*sh_av)[192] = (float(*)[192])(smem + 32768 + 2048);
    int ln = threadIdx.x >> 5, w = threadIdx.x & 31;
    for (int i = threadIdx.x; i < 2048; i += 256)
        ((uint4*)pk)[i] = ((const uint4*)Wupk)[i];
    for (int g = 0; g < 2; g++) {
        int n = blk * 16 + g * 8 + ln;
        bool valid = n < N;
        __syncthreads();
        if (valid) {
            sh_as[ln][w] = agg_s[n * 64 + w];
            sh_as[ln][32 + w] = agg_s[n * 64 + 32 + w];
#pragma unroll
            for (int i = 0; i < 6; i++)
                sh_av[ln][w * 6 + i] = agg_v[(size_t)n * 192 + w * 6 + i];
        }
        __syncthreads();
        if (!valid) continue;
        float4 at = *(const float4*)(attr + n * 4);
        float acc_s = 0.f, a0 = 0.f, a1 = 0.f, a2 = 0.f;
        for (int u = 0; u < 64; u++) {
            float gs = sh_as[ln][u];
            float g0 = sh_av[ln][u * 3 + 0];
            float g1 = sh_av[ln][u * 3 + 1];
            float g2 = sh_av[ln][u * 3 + 2];
            uint4 pv = *(const uint4*)(pk + u * 128 + w * 4);
            float w20x = bf2f((unsigned short)pv.x), w21x = bf2f((unsigned short)(pv.x >> 16));
            float w20y = bf2f((unsigned short)pv.y), w21y = bf2f((unsigned short)(pv.y >> 16));
            float w20z = bf2f((unsigned short)pv.z), w21z = bf2f((unsigned short)(pv.z >> 16));
            float w20w = bf2f((unsigned short)pv.w), w21w = bf2f((unsigned short)(pv.w >> 16));
            float d0 = at.x * w20x + at.y * w20y + at.z * w20z + at.w * w20w;
            float d1 = at.x * w21x + at.y * w21y + at.z * w21z + at.w * w21w;
            acc_s += gs * d0;
            a0 += g0 * d1; a1 += g1 * d1; a2 += g2 * d1;
        }
        float os = acc_s * NORM256_F;
        float sn = C_S_F * sc_s[n * 32 + w] + C_X_F * os;
        float sig = 1.0f / (1.0f + __expf(-sn));
        s[n * 32 + w] += sn * sig;   // silu(sn)
        float ov0 = a0 * NORM256_F, ov1 = a1 * NORM256_F, ov2 = a2 * NORM256_F;
        v[n * 96 + w * 3 + 0] += (C_S_F * sc_v[n * 96 + w * 3 + 0] + C_X_F * ov0) * sig;
        v[n * 96 + w * 3 + 1] += (C_S_F * sc_v[n * 96 + w * 3 + 1] + C_X_F * ov1) * sig;
        v[n * 96 + w * 3 + 2] += (C_S_F * sc_v[n * 96 + w * 3 + 2] + C_X_F * ov2) * sig;
    }
}

// ---------------------------------------------------------------- mega kernels
__global__ __launch_bounds__(256) void mega1(
    int nInit, int nSetup, int nCount,
    const float* __restrict__ x, float* __restrict__ s, float* __restrict__ v,
    const float* __restrict__ Wfc1, const float* __restrict__ Wfc2,
    const float* __restrict__ Wsc0, const float* __restrict__ Wl10,
    const float* __restrict__ Wsc1, const float* __restrict__ Wl11,
    const float* __restrict__ Wl20, const float* __restrict__ Wl21,
    float* __restrict__ Wfp, unsigned* __restrict__ Wupk,
    unsigned* __restrict__ tab,
    const int* __restrict__ edst, int* __restrict__ cnt, int N, int E) {
    int b = blockIdx.x;
    if (b < nInit) { init_sv_body(b, x, s, v, N); return; }
    b -= nInit;
    if (b < nSetup) {
        setup_weights_body(b, Wsc0, Wl10, Wsc1, Wl11, Wl20, Wl21, Wfp, Wupk);
        return;
    }
    b -= nSetup;
    if (b < nCount) { csr_count_body(b, edst, cnt, E); return; }
    b -= nCount;
    tab_gen_body(b, Wfc1, Wfc2, tab);
}

__global__ void csr_scan(const int* __restrict__ cnt, int* __restrict__ off,
                         int* __restrict__ cursor, int N) {
    __shared__ int sums[256];
    int t = threadIdx.x;
    int chunk = (N + 255) / 256;
    int lo = t * chunk, hi = lo + chunk; if (hi > N) hi = N;
    int s = 0;
    for (int i = lo; i < hi; i++) s += cnt[i];
    sums[t] = s;
    __syncthreads();
    for (int d = 1; d < 256; d <<= 1) {
        int v = (t >= d) ? sums[t - d] : 0;
        __syncthreads();
        sums[t] += v;
        __syncthreads();
    }
    int run = (t == 0) ? 0 : sums[t - 1];
    for (int i = lo; i < hi; i++) {
        off[i] = run; cursor[i] = run;
        run += cnt[i];
    }
}

// csr_fill || fctp(layer0, both paths) || zero agg ping-pong buffers
__global__ __launch_bounds__(256, 4) void mega2(
    int nFill, int nF,
    const int* __restrict__ edst, const int* __restrict__ esrc,
    const float* __restrict__ edge_vec, int* __restrict__ cursor,
    float* __restrict__ vec_csr, int E,
    const float* __restrict__ s, const float* __restrict__ v,
    const float* __restrict__ attr, const float* __restrict__ Wfp,
    float* __restrict__ sc_s, float* __restrict__ sc_v,
    float* __restrict__ xsv, int N,
    float* __restrict__ zero_base, int nZeroF4) {
    __shared__ __align__(16) char smem[35840];
    int b = blockIdx.x;
    if (b < nFill) {
        csr_fill_body(b, edst, esrc, edge_vec, cursor, vec_csr, E);
        return;
    }
    b -= nFill;
    if (b < 2 * nF) {
        node_fctp_body(b % nF, b / nF, s, v, attr, Wfp, sc_s, sc_v, xsv, N, smem);
        return;
    }
    b -= 2 * nF;
    int i = b * 256 + threadIdx.x;
    if (i < nZeroF4) {
        float4 z = {0.f, 0.f, 0.f, 0.f};
        ((float4*)zero_base)[i] = z;
    }
}

// ---------------------------------------------------------------- gather
// 2 waves per dst node (4 quarter-waves striding the node's CSR slots by 4).
// Per-edge weights regenerated inline from the w(len) table (coalesced lerp);
// no per-edge weight buffer exists anywhere. Atomic-free reduction:
// shfl + LDS + plain stores (each block owns its 2 nodes exclusively).
__global__ __launch_bounds__(256, 4) void gather_msgs(
    const int* __restrict__ off, const int* __restrict__ cnt,
    const unsigned* __restrict__ tab,
    const float* __restrict__ vec_csr, const float* __restrict__ xsv,
    float* __restrict__ agg_s, float* __restrict__ agg_v, int N) {
    __shared__ float red[2][8][32];
    int pair = threadIdx.x >> 7;
    int node = blockIdx.x * 2 + pair;
    int ql = threadIdx.x & 127;
    int quarter = ql >> 5;
    int u = ql & 31;
    bool active = node < N;
    int o = 0, deg = 0;
    if (active) { o = off[node]; deg = cnt[node]; }
    float as0 = 0, as1 = 0;
    float av00 = 0, av01 = 0, av02 = 0, av10 = 0, av11 = 0, av12 = 0;

    auto body = [&](int slot) {
        size_t p = (size_t)slot;
        float4 vv = *(const float4*)(vec_csr + p * 4);
        int src = __float_as_int(vv.w);
        float len = sqrtf(vv.x * vv.x + vv.y * vv.y + vv.z * vv.z);
        float rinv = SQRT3_F / (len + 1e-9f);
        float y0 = vv.x * rinv, y1 = vv.y * rinv, y2 = vv.z * rinv;
        // table lerp: w0..w3 at this edge's length
        float t = fminf(len, 3.99995f) * 128.0f;
        int ti = (int)t;
        float fr = t - (float)ti;
        const unsigned* tr = tab + ti * 64 + u;
        unsigned qa0 = tr[0],  qa1 = tr[32];     // row ti:   (w0,w2)[u], (w1,w3)[u]
        unsigned qb0 = tr[64], qb1 = tr[96];     // row ti+1
        float4 x4 = *(const float4*)(xsv + (size_t)src * 128 + u * 4);
        float wa0 = bf2f((unsigned short)qa0), wb0 = bf2f((unsigned short)qb0);
        float wc0 = bf2f((unsigned short)(qa0 >> 16)), wd0 = bf2f((unsigned short)(qb0 >> 16));
        float wa1 = bf2f((unsigned short)qa1), wb1 = bf2f((unsigned short)qb1);
        float wc1 = bf2f((unsigned short)(qa1 >> 16)), wd1 = bf2f((unsigned short)(qb1 >> 16));
        float wa = wa0 + fr * (wb0 - wa0);   // w0[u]
        float wc = wc0 + fr * (wd0 - wc0);   // w2[u]
        float wb = wa1 + fr * (wb1 - wa1);   // w1[u]
        float wd = wc1 + fr * (wd1 - wc1);   // w3[u]
        as0 += wa * x4.w;
        as1 += wb * (y0 * x4.x + y1 * x4.y + y2 * x4.z) * INV_SQRT3_F;
        float tt = wc * x4.w;
        av00 += tt * y0;  av01 += tt * y1;  av02 += tt * y2;
        av10 += wd * x4.x; av11 += wd * x4.y; av12 += wd * x4.z;
    };

    int i = quarter;
    for (; i + 4 < deg; i += 8) { body(o + i); body(o + i + 4); }
    for (; i < deg; i += 4) body(o + i);

    as0 += __shfl_down(as0, 32);  as1 += __shfl_down(as1, 32);
    av00 += __shfl_down(av00, 32); av01 += __shfl_down(av01, 32); av02 += __shfl_down(av02, 32);
    av10 += __shfl_down(av10, 32); av11 += __shfl_down(av11, 32); av12 += __shfl_down(av12, 32);

    int lane = threadIdx.x & 63;
    int upper_wave = (threadIdx.x >> 6) & 1;
    if (upper_wave && lane < 32) {
        red[pair][0][u] = as0;  red[pair][1][u] = as1;
        red[pair][2][u] = av00; red[pair][3][u] = av01; red[pair][4][u] = av02;
        red[pair][5][u] = av10; red[pair][6][u] = av11; red[pair][7][u] = av12;
    }
    __syncthreads();
    if (active && !upper_wave && lane < 32) {
        as0  += red[pair][0][u];  as1  += red[pair][1][u];
        av00 += red[pair][2][u];  av01 += red[pair][3][u];  av02 += red[pair][4][u];
        av10 += red[pair][5][u];  av11 += red[pair][6][u];  av12 += red[pair][7][u];
        agg_s[node * 64 + u]      = as0 * INV_SQRTNN_F;
        agg_s[node * 64 + 32 + u] = as1 * INV_SQRTNN_F;
        float* av = agg_v + (size_t)node * 192;
        av[u * 3 + 0]      = av00 * INV_SQRTNN_F;
        av[u * 3 + 1]      = av01 * INV_SQRTNN_F;
        av[u * 3 + 2]      = av02 * INV_SQRTNN_F;
        av[96 + u * 3 + 0] = av10 * INV_SQRTNN_F;
        av[96 + u * 3 + 1] = av11 * INV_SQRTNN_F;
        av[96 + u * 3 + 2] = av12 * INV_SQRTNN_F;
    }
}

// ------------------------------- node update (layer l) + fctp (layer l+1)
__global__ __launch_bounds__(256, 4) void update_fctp(
    const float* __restrict__ agg_s, const float* __restrict__ agg_v,
    const float* __restrict__ attr, const unsigned* __restrict__ Wupk,
    float* __restrict__ sc_s, float* __restrict__ sc_v,
    float* __restrict__ s, float* __restrict__ v,
    const float* __restrict__ Wfp_next, float* __restrict__ xsv,
    int N, int do_fctp) {
    __shared__ __align__(16) char smem[40960];
    node_update_body(blockIdx.x, agg_s, agg_v, attr, Wupk, sc_s, sc_v, s, v, N, smem);
    if (do_fctp) {
        __syncthreads();   // pk/sh_as reads done; s,v global writes drained
        node_fctp_body(blockIdx.x, 0, s, v, attr, Wfp_next, sc_s, sc_v, xsv, N, smem);
        __syncthreads();   // w0/w1 reads done before path-1 reload
        node_fctp_body(blockIdx.x, 1, s, v, attr, Wfp_next, sc_s, sc_v, xsv, N, smem);
    }
}

// ---------------------------------------------------------------- readout
__global__ __launch_bounds__(256) void readout(
    const float* __restrict__ s, const float* __restrict__ attr,
    const float* __restrict__ Wread, const int* __restrict__ batch,
    float* __restrict__ out, int N, float pool_scale) {
    __shared__ float wr[2048];
    __shared__ float red[NGRAPH * 16];
    for (int i = threadIdx.x; i < 2048; i += 256) wr[i] = Wread[i];
    if (threadIdx.x < NGRAPH * 16) red[threadIdx.x] = 0.f;
    __syncthreads();
    int ln = threadIdx.x >> 4, w = threadIdx.x & 15;
    for (int g = 0; g < 4; g++) {
        int n = blockIdx.x * 64 + g * 16 + ln;
        if (n < N) {
            float4 at = *(const float4*)(attr + n * 4);
            float fa[4] = {at.x, at.y, at.z, at.w};
            float acc = 0.f;
            for (int u = 0; u < 32; u++) {
                float su = s[n * 32 + u];
                int base = u * 64 + w;
#pragma unroll
                for (int a = 0; a < 4; a++) acc += su * fa[a] * wr[base + a * 16];
            }
            atomicAdd(&red[batch[n] * 16 + w], acc);
        }
    }
    __syncthreads();
    if (threadIdx.x < NGRAPH * 16) {
        float val = red[threadIdx.x];
        if (val != 0.f)
            atomicAdd(&out[threadIdx.x], val * NORM128_F * pool_scale);
    }
}

// ---------------------------------------------------------------- launch
extern "C" void kernel_launch(void* const* d_in, const int* in_sizes, int n_in,
                              void* d_out, int out_size, void* d_ws, size_t ws_size,
                              hipStream_t stream) {
    const float* x        = (const float*)d_in[0];
    const float* nattr    = (const float*)d_in[1];
    const float* edge_vec = (const float*)d_in[2];
    const int*   batch    = (const int*)d_in[3];
    const int*   esrc     = (const int*)d_in[4];
    const int*   edst     = (const int*)d_in[5];
    const float* Wsc0  = (const float*)d_in[6];
    const float* Wsc1  = (const float*)d_in[7];
    const float* Wl10  = (const float*)d_in[8];
    const float* Wl11  = (const float*)d_in[9];
    const float* Wfc1  = (const float*)d_in[10];
    const float* Wfc2  = (const float*)d_in[11];
    const float* Wl20  = (const float*)d_in[12];
    const float* Wl21  = (const float*)d_in[13];
    const float* Wread = (const float*)d_in[14];

    int N = in_sizes[0] / (MUL * 4);
    int E = in_sizes[2] / 3;

    float* p = (float*)d_ws;
    float* vec_csr = p; p += (size_t)E * 4;     // {ex,ey,ez,src-bits}
    unsigned* tab = (unsigned*)p; p += 2 * NT * 64;  // w(len) tables, packed bf16
    float* Wfp    = p; p += 32768;              // 2 layers x 4 matrices x 4096
    unsigned* Wupk = (unsigned*)p; p += 16384;  // 2 layers x 8192 packed pair dwords
    float* s_buf  = p; p += (size_t)N * 32;
    float* v_buf  = p; p += (size_t)N * 96;
    float* sc_s   = p; p += (size_t)N * 32;
    float* sc_v   = p; p += (size_t)N * 96;
    float* xsv    = p; p += (size_t)N * 128;    // {xv0,xv1,xv2,xs} per (n,u)
    float* aggA_s = p; p += (size_t)N * 64;     // ping-pong agg buffers, contiguous
    float* aggA_v = p; p += (size_t)N * 192;
    float* aggB_s = p; p += (size_t)N * 64;
    float* aggB_v = p; p += (size_t)N * 192;
    int* cnt     = (int*)p; p += N;
    int* off     = (int*)p; p += N;
    int* cursor  = (int*)p; p += N;

    hipMemsetAsync(d_out, 0, (size_t)out_size * sizeof(float), stream);
    hipMemsetAsync(cnt, 0, (size_t)N * sizeof(int), stream);

    int nInit  = (N * 128 + 255) / 256;
    int nSetup = 192;
    int nCount = (E + 255) / 256;
    int nTab   = (2 * NT * 8 + 255) / 256;
    mega1<<<nInit + nSetup + nCount + nTab, 256, 0, stream>>>(
        nInit, nSetup, nCount, x, s_buf, v_buf,
        Wfc1, Wfc2, Wsc0, Wl10, Wsc1, Wl11, Wl20, Wl21,
        Wfp, Wupk, tab, edst, cnt, N, E);

    csr_scan<<<1, 256, 0, stream>>>(cnt, off, cursor, N);

    int nFill = (E + 255) / 256;
    int nF = (N + 15) / 16;
    int nZeroF4 = N * 128;                      // both agg ping-pong buffers
    int nZeroBlk = (nZeroF4 + 255) / 256;
    mega2<<<nFill + 2 * nF + nZeroBlk, 256, 0, stream>>>(
        nFill, nF, edst, esrc, edge_vec, cursor, vec_csr, E,
        s_buf, v_buf, nattr, Wfp, sc_s, sc_v, xsv, N, aggA_s, nZeroF4);

    int nG = (N + 1) / 2;

    // ---- layer 0
    gather_msgs<<<nG, 256, 0, stream>>>(
        off, cnt, tab, vec_csr, xsv, aggA_s, aggA_v, N);
    update_fctp<<<nF, 256, 0, stream>>>(
        aggA_s, aggA_v, nattr, Wupk, sc_s, sc_v, s_buf, v_buf,
        Wfp + 16384, xsv, N, 1);

    // ---- layer 1
    gather_msgs<<<nG, 256, 0, stream>>>(
        off, cnt, tab + NT * 64, vec_csr, xsv, aggB_s, aggB_v, N);
    update_fctp<<<nF, 256, 0, stream>>>(
        aggB_s, aggB_v, nattr, Wupk + 8192, sc_s, sc_v, s_buf, v_buf,
        (const float*)0, xsv, N, 0);

    float pool_scale = (float)(1.0 / sqrt((double)N / (double)NGRAPH));
    readout<<<(N + 63) / 64, 256, 0, stream>>>(
        s_buf, nattr, Wread, batch, (float*)d_out, N, pool_scale);
}

// Round 10
// 291.929 us; speedup vs baseline: 1.3472x; 1.0878x over previous
//
#include <hip/hip_runtime.h>
#include <math.h>

#define MUL 32
#define NATTR 4
#define NBASIS 10
#define HID 64
#define OUT_DIM 16
#define NGRAPH 8
#define NT 513      // w(len) table entries: len = i/128, i in [0,512]

#define PI_F 3.14159265358979323846f
#define SQRT3_F 1.7320508075688772f
#define INV_SQRT3_F 0.5773502691896258f
#define INV_SQRT10_F 0.31622776601683794f
#define INV_SQRTNN_F 0.17677669529663687f   // 1/sqrt(32)
#define NORM128_F 0.08838834764831845f      // 1/sqrt(128)
#define NORM256_F 0.0625f                   // 1/sqrt(256)
#define C_S_F 0.3826834323650898f           // sin(pi/8)
#define C_X_F 0.9238795325112867f           // cos(pi/8)
#define CSTEP_F (4.0f/9.0f)                 // linspace(0,4,10) step

__device__ inline unsigned short f2bf(float x) {
    unsigned u = __float_as_uint(x);
    u += 0x7FFF + ((u >> 16) & 1);          // round-to-nearest-even
    return (unsigned short)(u >> 16);
}
__device__ inline float bf2f(unsigned short h) {
    return __uint_as_float(((unsigned)h) << 16);
}

// ---------------------------------------------------------------- bodies
__device__ __forceinline__ void init_sv_body(
    int blk, const float* __restrict__ x,
    float* __restrict__ s, float* __restrict__ v, int N) {
    int i = blk * 256 + threadIdx.x;
    if (i >= N * 128) return;
    int n = i >> 7, c = i & 127;
    float val = x[i];
    if (c < 32) s[n * 32 + c] = val;
    else        v[n * 96 + (c - 32)] = val;
}

__device__ __forceinline__ void setup_weights_body(
    int blk,
    const float* __restrict__ Wsc0, const float* __restrict__ Wl10,
    const float* __restrict__ Wsc1, const float* __restrict__ Wl11,
    const float* __restrict__ Wl20, const float* __restrict__ Wl21,
    float* __restrict__ Wfp, unsigned* __restrict__ Wupk) {
    int i = blk * 256 + threadIdx.x;
    if (i < 32768) {
        int idx = i >> 12;          // l*4 + m
        int r = i & 4095;
        int l = idx >> 2, m = idx & 3;
        const float* base = (m == 0 ? Wsc0 : m == 1 ? Wl10 : m == 2 ? Wsc1 : Wl11)
                            + l * 4096;
        int u = r >> 7, rr = r & 127, a = rr >> 5, ww = rr & 31;
        Wfp[idx * 4096 + u * 128 + ww * 4 + a] = base[r];
    } else if (i < 49152) {
        int j = i - 32768;
        int l = j >> 13;
        int r = j & 8191;
        int u = r >> 7, rr = r & 127, a = rr >> 5, ww = rr & 31;
        unsigned lo = f2bf(Wl20[l * 8192 + r]);
        unsigned hi = f2bf(Wl21[l * 8192 + r]);
        Wupk[l * 8192 + u * 128 + ww * 4 + a] = lo | (hi << 16);
    }
}

// w(len) table generator, cooperative: one 64-thread group per table row.
// Phase 1: thread n computes h[n] -> LDS (coalesced W1 read).
// Phase 2: thread j computes w0[j], w1[j] via 64-step dot over LDS h with
// coalesced W2 reads. 4 rows per 256-thread block.
__device__ __forceinline__ void tab_gen_body(
    int blk, const float* __restrict__ Wfc1, const float* __restrict__ Wfc2,
    unsigned* __restrict__ tab, float (*sh_h)[64]) {
    int g = threadIdx.x >> 6;       // row group 0..3
    int n = threadIdx.x & 63;       // h index / output j
    int row = blk * 4 + g;
    bool valid = row < 2 * NT;
    int l = valid ? row / NT : 0;
    int i = valid ? row % NT : 0;
    float len = (float)i * (1.0f / 128.0f);
    float uu = len * 0.5f - 2.0f;
    float cut = (uu > 0.0f) ? 0.0f
              : ((uu < -1.0f) ? 1.0f : 0.5f * (1.0f - __cosf(PI_F * uu)));
    const float* W1 = Wfc1 + l * 640;
    float a = 0.f;
#pragma unroll
    for (int k = 0; k < 10; k++) {
        float d = (len - k * CSTEP_F) * 2.5f;
        float e = __expf(-d * d) * cut;
        a += e * W1[k * 64 + n];
    }
    a *= INV_SQRT10_F;
    sh_h[g][n] = a / (1.0f + __expf(-a));
    __syncthreads();
    if (!valid) return;
    const float* W2 = Wfc2 + l * 8192;
    float w0 = 0.f, w1 = 0.f;
#pragma unroll 8
    for (int nn = 0; nn < 64; nn++) {
        float hn = sh_h[g][nn];
        w0 += hn * W2[nn * 128 + n];
        w1 += hn * W2[nn * 128 + 64 + n];
    }
    w0 *= 0.125f; w1 *= 0.125f;
    tab[(size_t)l * NT * 64 + i * 64 + n] =
        (unsigned)f2bf(w0) | ((unsigned)f2bf(w1) << 16);
}

__device__ __forceinline__ void csr_count_body(
    int blk, const int* __restrict__ edst, int* __restrict__ cnt, int E) {
    int e = blk * 256 + threadIdx.x;
    if (e < E) atomicAdd(&cnt[edst[e]], 1);
}

__device__ __forceinline__ void csr_fill_body(
    int blk, const int* __restrict__ edst, const int* __restrict__ esrc,
    const float* __restrict__ edge_vec, int* __restrict__ cursor,
    float* __restrict__ vec_csr, int E) {
    int e = blk * 256 + threadIdx.x;
    if (e < E) {
        int d = edst[e];
        int p = atomicAdd(&cursor[d], 1);
        float4 vv = {edge_vec[e * 3 + 0], edge_vec[e * 3 + 1], edge_vec[e * 3 + 2],
                     __int_as_float(esrc[e])};
        *(float4*)(vec_csr + (size_t)p * 4) = vv;
    }
}

// node fctp: 16 nodes/block; smem: [0,16K) w0 | [16K,32K) w1 | [32K,35K) sh
__device__ __forceinline__ void node_fctp_body(
    int blk, int path,
    const float* __restrict__ s, const float* __restrict__ v,
    const float* __restrict__ attr, const float* __restrict__ Wfp,
    float* __restrict__ sc_s, float* __restrict__ sc_v,
    float* __restrict__ xsv, int N, char* smem) {
    float* w0 = (float*)smem;
    float* w1 = (float*)(smem + 16384);
    float (*sh)[96] = (float(*)[96])(smem + 32768);
    int ln = threadIdx.x >> 5, w = threadIdx.x & 31;
    const float4* W0p = (const float4*)(Wfp + path * 8192);
    const float4* W1p = (const float4*)(Wfp + path * 8192 + 4096);
    for (int i = threadIdx.x; i < 1024; i += 256) {
        ((float4*)w0)[i] = W0p[i];
        ((float4*)w1)[i] = W1p[i];
    }
    for (int g = 0; g < 2; g++) {
        int n = blk * 16 + g * 8 + ln;
        bool valid = n < N;
        __syncthreads();
        if (valid) {
            if (path == 0) {
                sh[ln][w] = s[n * 32 + w];
            } else {
                sh[ln][w * 3 + 0] = v[n * 96 + w * 3 + 0];
                sh[ln][w * 3 + 1] = v[n * 96 + w * 3 + 1];
                sh[ln][w * 3 + 2] = v[n * 96 + w * 3 + 2];
            }
        }
        __syncthreads();
        if (!valid) continue;
        float4 at = *(const float4*)(attr + n * 4);
        if (path == 0) {
            float acc0 = 0.f, acc1 = 0.f;
            for (int u = 0; u < 32; u++) {
                float su = sh[ln][u];
                float4 W0v = *(const float4*)(w0 + u * 128 + w * 4);
                float4 W1v = *(const float4*)(w1 + u * 128 + w * 4);
                float d0 = at.x * W0v.x + at.y * W0v.y + at.z * W0v.z + at.w * W0v.w;
                float d1 = at.x * W1v.x + at.y * W1v.y + at.z * W1v.z + at.w * W1v.w;
                acc0 += su * d0;
                acc1 += su * d1;
            }
            sc_s[n * 32 + w] = acc0 * NORM128_F;
            xsv[(size_t)n * 128 + w * 4 + 3] = acc1 * NORM128_F;
        } else {
            float a00 = 0, a01 = 0, a02 = 0, a10 = 0, a11 = 0, a12 = 0;
            for (int u = 0; u < 32; u++) {
                float vu0 = sh[ln][u * 3 + 0];
                float vu1 = sh[ln][u * 3 + 1];
                float vu2 = sh[ln][u * 3 + 2];
                float4 W0v = *(const float4*)(w0 + u * 128 + w * 4);
                float4 W1v = *(const float4*)(w1 + u * 128 + w * 4);
                float d0 = at.x * W0v.x + at.y * W0v.y + at.z * W0v.z + at.w * W0v.w;
                float d1 = at.x * W1v.x + at.y * W1v.y + at.z * W1v.z + at.w * W1v.w;
                a00 += vu0 * d0; a01 += vu1 * d0; a02 += vu2 * d0;
                a10 += vu0 * d1; a11 += vu1 * d1; a12 += vu2 * d1;
            }
            sc_v[n * 96 + w * 3 + 0] = a00 * NORM128_F;
            sc_v[n * 96 + w * 3 + 1] = a01 * NORM128_F;
            sc_v[n * 96 + w * 3 + 2] = a02 * NORM128_F;
            float* xp = xsv + (size_t)n * 128 + w * 4;
            xp[0] = a10 * NORM128_F;
            xp[1] = a11 * NORM128_F;
            xp[2] = a12 * NORM128_F;
        }
    }
}

// node update: smem [0,32K) pk | [32K,34K) sh_as | [34K,40K) sh_av
__device__ __forceinline__ void node_update_body(
    int blk, const float* __restrict__ agg_s, const float* __restrict__ agg_v,
    const float* __restrict__ attr, const unsigned* __restrict__ Wupk,
    const float* __restrict__ sc_s, const float* __restrict__ sc_v,
    float* __restrict__ s, float* __restrict__ v, int N, char* smem) {
    unsigned* pk = (unsigned*)smem;
    float (*sh_as)[64]  = (float(*)[64])(smem + 32768);
    float (*sh_av)[192] = (float(*)[192])(smem + 32768 + 2048);
    int ln = threadIdx.x >> 5, w = threadIdx.x & 31;
    for (int i = threadIdx.x; i < 2048; i += 256)
        ((uint4*)pk)[i] = ((const uint4*)Wupk)[i];
    for (int g = 0; g < 2; g++) {
        int n = blk * 16 + g * 8 + ln;
        bool valid = n < N;
        __syncthreads();
        if (valid) {
            sh_as[ln][w] = agg_s[n * 64 + w];
            sh_as[ln][32 + w] = agg_s[n * 64 + 32 + w];
#pragma unroll
            for (int i = 0; i < 6; i++)
                sh_av[ln][w * 6 + i] = agg_v[(size_t)n * 192 + w * 6 + i];
        }
        __syncthreads();
        if (!valid) continue;
        float4 at = *(const float4*)(attr + n * 4);
        float acc_s = 0.f, a0 = 0.f, a1 = 0.f, a2 = 0.f;
        for (int u = 0; u < 64; u++) {
            float gs = sh_as[ln][u];
            float g0 = sh_av[ln][u * 3 + 0];
            float g1 = sh_av[ln][u * 3 + 1];
            float g2 = sh_av[ln][u * 3 + 2];
            uint4 pv = *(const uint4*)(pk + u * 128 + w * 4);
            float w20x = bf2f((unsigned short)pv.x), w21x = bf2f((unsigned short)(pv.x >> 16));
            float w20y = bf2f((unsigned short)pv.y), w21y = bf2f((unsigned short)(pv.y >> 16));
            float w20z = bf2f((unsigned short)pv.z), w21z = bf2f((unsigned short)(pv.z >> 16));
            float w20w = bf2f((unsigned short)pv.w), w21w = bf2f((unsigned short)(pv.w >> 16));
            float d0 = at.x * w20x + at.y * w20y + at.z * w20z + at.w * w20w;
            float d1 = at.x * w21x + at.y * w21y + at.z * w21z + at.w * w21w;
            acc_s += gs * d0;
            a0 += g0 * d1; a1 += g1 * d1; a2 += g2 * d1;
        }
        float os = acc_s * NORM256_F;
        float sn = C_S_F * sc_s[n * 32 + w] + C_X_F * os;
        float sig = 1.0f / (1.0f + __expf(-sn));
        s[n * 32 + w] += sn * sig;   // silu(sn)
        float ov0 = a0 * NORM256_F, ov1 = a1 * NORM256_F, ov2 = a2 * NORM256_F;
        v[n * 96 + w * 3 + 0] += (C_S_F * sc_v[n * 96 + w * 3 + 0] + C_X_F * ov0) * sig;
        v[n * 96 + w * 3 + 1] += (C_S_F * sc_v[n * 96 + w * 3 + 1] + C_X_F * ov1) * sig;
        v[n * 96 + w * 3 + 2] += (C_S_F * sc_v[n * 96 + w * 3 + 2] + C_X_F * ov2) * sig;
    }
}

// ---------------------------------------------------------------- mega kernels
// tab blocks FIRST so the table generation starts immediately.
__global__ __launch_bounds__(256) void mega1(
    int nTab, int nInit, int nSetup,
    const float* __restrict__ x, float* __restrict__ s, float* __restrict__ v,
    const float* __restrict__ Wfc1, const float* __restrict__ Wfc2,
    const float* __restrict__ Wsc0, const float* __restrict__ Wl10,
    const float* __restrict__ Wsc1, const float* __restrict__ Wl11,
    const float* __restrict__ Wl20, const float* __restrict__ Wl21,
    float* __restrict__ Wfp, unsigned* __restrict__ Wupk,
    unsigned* __restrict__ tab,
    const int* __restrict__ edst, int* __restrict__ cnt, int N, int E) {
    __shared__ float sh_h[4][64];
    int b = blockIdx.x;
    if (b < nTab) { tab_gen_body(b, Wfc1, Wfc2, tab, sh_h); return; }
    b -= nTab;
    if (b < nInit) { init_sv_body(b, x, s, v, N); return; }
    b -= nInit;
    if (b < nSetup) {
        setup_weights_body(b, Wsc0, Wl10, Wsc1, Wl11, Wl20, Wl21, Wfp, Wupk);
        return;
    }
    b -= nSetup;
    csr_count_body(b, edst, cnt, E);
}

__global__ void csr_scan(const int* __restrict__ cnt, int* __restrict__ off,
                         int* __restrict__ cursor, int N) {
    __shared__ int sums[256];
    int t = threadIdx.x;
    int chunk = (N + 255) / 256;
    int lo = t * chunk, hi = lo + chunk; if (hi > N) hi = N;
    int s = 0;
    for (int i = lo; i < hi; i++) s += cnt[i];
    sums[t] = s;
    __syncthreads();
    for (int d = 1; d < 256; d <<= 1) {
        int v = (t >= d) ? sums[t - d] : 0;
        __syncthreads();
        sums[t] += v;
        __syncthreads();
    }
    int run = (t == 0) ? 0 : sums[t - 1];
    for (int i = lo; i < hi; i++) {
        off[i] = run; cursor[i] = run;
        run += cnt[i];
    }
}

// csr_fill || fctp(layer0, both paths) || zero agg ping-pong buffers
__global__ __launch_bounds__(256, 4) void mega2(
    int nFill, int nF,
    const int* __restrict__ edst, const int* __restrict__ esrc,
    const float* __restrict__ edge_vec, int* __restrict__ cursor,
    float* __restrict__ vec_csr, int E,
    const float* __restrict__ s, const float* __restrict__ v,
    const float* __restrict__ attr, const float* __restrict__ Wfp,
    float* __restrict__ sc_s, float* __restrict__ sc_v,
    float* __restrict__ xsv, int N,
    float* __restrict__ zero_base, int nZeroF4) {
    __shared__ __align__(16) char smem[35840];
    int b = blockIdx.x;
    if (b < nFill) {
        csr_fill_body(b, edst, esrc, edge_vec, cursor, vec_csr, E);
        return;
    }
    b -= nFill;
    if (b < 2 * nF) {
        node_fctp_body(b % nF, b / nF, s, v, attr, Wfp, sc_s, sc_v, xsv, N, smem);
        return;
    }
    b -= 2 * nF;
    int i = b * 256 + threadIdx.x;
    if (i < nZeroF4) {
        float4 z = {0.f, 0.f, 0.f, 0.f};
        ((float4*)zero_base)[i] = z;
    }
}

// ---------------------------------------------------------------- gather
// 2 waves per dst node (4 quarter-waves striding the node's CSR slots by 4).
// Per-edge weights regenerated inline from the w(len) table (coalesced lerp);
// no per-edge weight buffer exists anywhere. Atomic-free reduction:
// shfl + LDS + plain stores (each block owns its 2 nodes exclusively).
__global__ __launch_bounds__(256, 4) void gather_msgs(
    const int* __restrict__ off, const int* __restrict__ cnt,
    const unsigned* __restrict__ tab,
    const float* __restrict__ vec_csr, const float* __restrict__ xsv,
    float* __restrict__ agg_s, float* __restrict__ agg_v, int N) {
    __shared__ float red[2][8][32];
    int pair = threadIdx.x >> 7;
    int node = blockIdx.x * 2 + pair;
    int ql = threadIdx.x & 127;
    int quarter = ql >> 5;
    int u = ql & 31;
    bool active = node < N;
    int o = 0, deg = 0;
    if (active) { o = off[node]; deg = cnt[node]; }
    float as0 = 0, as1 = 0;
    float av00 = 0, av01 = 0, av02 = 0, av10 = 0, av11 = 0, av12 = 0;

    auto body = [&](int slot) {
        size_t p = (size_t)slot;
        float4 vv = *(const float4*)(vec_csr + p * 4);
        int src = __float_as_int(vv.w);
        float len = sqrtf(vv.x * vv.x + vv.y * vv.y + vv.z * vv.z);
        float rinv = SQRT3_F / (len + 1e-9f);
        float y0 = vv.x * rinv, y1 = vv.y * rinv, y2 = vv.z * rinv;
        // table lerp: w0..w3 at this edge's length
        float t = fminf(len, 3.99995f) * 128.0f;
        int ti = (int)t;
        float fr = t - (float)ti;
        const unsigned* tr = tab + ti * 64 + u;
        unsigned qa0 = tr[0],  qa1 = tr[32];     // row ti:   (w0,w2)[u], (w1,w3)[u]
        unsigned qb0 = tr[64], qb1 = tr[96];     // row ti+1
        float4 x4 = *(const float4*)(xsv + (size_t)src * 128 + u * 4);
        float wa0 = bf2f((unsigned short)qa0), wb0 = bf2f((unsigned short)qb0);
        float wc0 = bf2f((unsigned short)(qa0 >> 16)), wd0 = bf2f((unsigned short)(qb0 >> 16));
        float wa1 = bf2f((unsigned short)qa1), wb1 = bf2f((unsigned short)qb1);
        float wc1 = bf2f((unsigned short)(qa1 >> 16)), wd1 = bf2f((unsigned short)(qb1 >> 16));
        float wa = wa0 + fr * (wb0 - wa0);   // w0[u]
        float wc = wc0 + fr * (wd0 - wc0);   // w2[u]
        float wb = wa1 + fr * (wb1 - wa1);   // w1[u]
        float wd = wc1 + fr * (wd1 - wc1);   // w3[u]
        as0 += wa * x4.w;
        as1 += wb * (y0 * x4.x + y1 * x4.y + y2 * x4.z) * INV_SQRT3_F;
        float tt = wc * x4.w;
        av00 += tt * y0;  av01 += tt * y1;  av02 += tt * y2;
        av10 += wd * x4.x; av11 += wd * x4.y; av12 += wd * x4.z;
    };

    int i = quarter;
    for (; i + 4 < deg; i += 8) { body(o + i); body(o + i + 4); }
    for (; i < deg; i += 4) body(o + i);

    as0 += __shfl_down(as0, 32);  as1 += __shfl_down(as1, 32);
    av00 += __shfl_down(av00, 32); av01 += __shfl_down(av01, 32); av02 += __shfl_down(av02, 32);
    av10 += __shfl_down(av10, 32); av11 += __shfl_down(av11, 32); av12 += __shfl_down(av12, 32);

    int lane = threadIdx.x & 63;
    int upper_wave = (threadIdx.x >> 6) & 1;
    if (upper_wave && lane < 32) {
        red[pair][0][u] = as0;  red[pair][1][u] = as1;
        red[pair][2][u] = av00; red[pair][3][u] = av01; red[pair][4][u] = av02;
        red[pair][5][u] = av10; red[pair][6][u] = av11; red[pair][7][u] = av12;
    }
    __syncthreads();
    if (active && !upper_wave && lane < 32) {
        as0  += red[pair][0][u];  as1  += red[pair][1][u];
        av00 += red[pair][2][u];  av01 += red[pair][3][u];  av02 += red[pair][4][u];
        av10 += red[pair][5][u];  av11 += red[pair][6][u];  av12 += red[pair][7][u];
        agg_s[node * 64 + u]      = as0 * INV_SQRTNN_F;
        agg_s[node * 64 + 32 + u] = as1 * INV_SQRTNN_F;
        float* av = agg_v + (size_t)node * 192;
        av[u * 3 + 0]      = av00 * INV_SQRTNN_F;
        av[u * 3 + 1]      = av01 * INV_SQRTNN_F;
        av[u * 3 + 2]      = av02 * INV_SQRTNN_F;
        av[96 + u * 3 + 0] = av10 * INV_SQRTNN_F;
        av[96 + u * 3 + 1] = av11 * INV_SQRTNN_F;
        av[96 + u * 3 + 2] = av12 * INV_SQRTNN_F;
    }
}

// ------------------------------- node update (layer l) + fctp (layer l+1)
__global__ __launch_bounds__(256, 4) void update_fctp(
    const float* __restrict__ agg_s, const float* __restrict__ agg_v,
    const float* __restrict__ attr, const unsigned* __restrict__ Wupk,
    float* __restrict__ sc_s, float* __restrict__ sc_v,
    float* __restrict__ s, float* __restrict__ v,
    const float* __restrict__ Wfp_next, float* __restrict__ xsv,
    int N, int do_fctp) {
    __shared__ __align__(16) char smem[40960];
    node_update_body(blockIdx.x, agg_s, agg_v, attr, Wupk, sc_s, sc_v, s, v, N, smem);
    if (do_fctp) {
        __syncthreads();   // pk/sh_as reads done; s,v global writes drained
        node_fctp_body(blockIdx.x, 0, s, v, attr, Wfp_next, sc_s, sc_v, xsv, N, smem);
        __syncthreads();   // w0/w1 reads done before path-1 reload
        node_fctp_body(blockIdx.x, 1, s, v, attr, Wfp_next, sc_s, sc_v, xsv, N, smem);
    }
}

// ---------------------------------------------------------------- readout
__global__ __launch_bounds__(256) void readout(
    const float* __restrict__ s, const float* __restrict__ attr,
    const float* __restrict__ Wread, const int* __restrict__ batch,
    float* __restrict__ out, int N, float pool_scale) {
    __shared__ float wr[2048];
    __shared__ float red[NGRAPH * 16];
    for (int i = threadIdx.x; i < 2048; i += 256) wr[i] = Wread[i];
    if (threadIdx.x < NGRAPH * 16) red[threadIdx.x] = 0.f;
    __syncthreads();
    int ln = threadIdx.x >> 4, w = threadIdx.x & 15;
    for (int g = 0; g < 4; g++) {
        int n = blockIdx.x * 64 + g * 16 + ln;
        if (n < N) {
            float4 at = *(const float4*)(attr + n * 4);
            float fa[4] = {at.x, at.y, at.z, at.w};
            float acc = 0.f;
            for (int u = 0; u < 32; u++) {
                float su = s[n * 32 + u];
                int base = u * 64 + w;
#pragma unroll
                for (int a = 0; a < 4; a++) acc += su * fa[a] * wr[base + a * 16];
            }
            atomicAdd(&red[batch[n] * 16 + w], acc);
        }
    }
    __syncthreads();
    if (threadIdx.x < NGRAPH * 16) {
        float val = red[threadIdx.x];
        if (val != 0.f)
            atomicAdd(&out[threadIdx.x], val * NORM128_F * pool_scale);
    }
}

// ---------------------------------------------------------------- launch
extern "C" void kernel_launch(void* const* d_in, const int* in_sizes, int n_in,
                              void* d_out, int out_size, void* d_ws, size_t ws_size,
                              hipStream_t stream) {
    const float* x        = (const float*)d_in[0];
    const float* nattr    = (const float*)d_in[1];
    const float* edge_vec = (const float*)d_in[2];
    const int*   batch    = (const int*)d_in[3];
    const int*   esrc     = (const int*)d_in[4];
    const int*   edst     = (const int*)d_in[5];
    const float* Wsc0  = (const float*)d_in[6];
    const float* Wsc1  = (const float*)d_in[7];
    const float* Wl10  = (const float*)d_in[8];
    const float* Wl11  = (const float*)d_in[9];
    const float* Wfc1  = (const float*)d_in[10];
    const float* Wfc2  = (const float*)d_in[11];
    const float* Wl20  = (const float*)d_in[12];
    const float* Wl21  = (const float*)d_in[13];
    const float* Wread = (const float*)d_in[14];

    int N = in_sizes[0] / (MUL * 4);
    int E = in_sizes[2] / 3;

    float* p = (float*)d_ws;
    float* vec_csr = p; p += (size_t)E * 4;     // {ex,ey,ez,src-bits}
    unsigned* tab = (unsigned*)p; p += 2 * NT * 64;  // w(len) tables, packed bf16
    float* Wfp    = p; p += 32768;              // 2 layers x 4 matrices x 4096
    unsigned* Wupk = (unsigned*)p; p += 16384;  // 2 layers x 8192 packed pair dwords
    float* s_buf  = p; p += (size_t)N * 32;
    float* v_buf  = p; p += (size_t)N * 96;
    float* sc_s   = p; p += (size_t)N * 32;
    float* sc_v   = p; p += (size_t)N * 96;
    float* xsv    = p; p += (size_t)N * 128;    // {xv0,xv1,xv2,xs} per (n,u)
    float* aggA_s = p; p += (size_t)N * 64;     // ping-pong agg buffers, contiguous
    float* aggA_v = p; p += (size_t)N * 192;
    float* aggB_s = p; p += (size_t)N * 64;
    float* aggB_v = p; p += (size_t)N * 192;
    int* cnt     = (int*)p; p += N;
    int* off     = (int*)p; p += N;
    int* cursor  = (int*)p; p += N;

    hipMemsetAsync(d_out, 0, (size_t)out_size * sizeof(float), stream);
    hipMemsetAsync(cnt, 0, (size_t)N * sizeof(int), stream);

    int nTab   = (2 * NT + 3) / 4;              // 4 rows per block
    int nInit  = (N * 128 + 255) / 256;
    int nSetup = 192;
    int nCount = (E + 255) / 256;
    mega1<<<nTab + nInit + nSetup + nCount, 256, 0, stream>>>(
        nTab, nInit, nSetup, x, s_buf, v_buf,
        Wfc1, Wfc2, Wsc0, Wl10, Wsc1, Wl11, Wl20, Wl21,
        Wfp, Wupk, tab, edst, cnt, N, E);

    csr_scan<<<1, 256, 0, stream>>>(cnt, off, cursor, N);

    int nFill = (E + 255) / 256;
    int nF = (N + 15) / 16;
    int nZeroF4 = N * 128;                      // both agg ping-pong buffers
    int nZeroBlk = (nZeroF4 + 255) / 256;
    mega2<<<nFill + 2 * nF + nZeroBlk, 256, 0, stream>>>(
        nFill, nF, edst, esrc, edge_vec, cursor, vec_csr, E,
        s_buf, v_buf, nattr, Wfp, sc_s, sc_v, xsv, N, aggA_s, nZeroF4);

    int nG = (N + 1) / 2;

    // ---- layer 0
    gather_msgs<<<nG, 256, 0, stream>>>(
        off, cnt, tab, vec_csr, xsv, aggA_s, aggA_v, N);
    update_fctp<<<nF, 256, 0, stream>>>(
        aggA_s, aggA_v, nattr, Wupk, sc_s, sc_v, s_buf, v_buf,
        Wfp + 16384, xsv, N, 1);

    // ---- layer 1
    gather_msgs<<<nG, 256, 0, stream>>>(
        off, cnt, tab + NT * 64, vec_csr, xsv, aggB_s, aggB_v, N);
    update_fctp<<<nF, 256, 0, stream>>>(
        aggB_s, aggB_v, nattr, Wupk + 8192, sc_s, sc_v, s_buf, v_buf,
        (const float*)0, xsv, N, 0);

    float pool_scale = (float)(1.0 / sqrt((double)N / (double)NGRAPH));
    readout<<<(N + 63) / 64, 256, 0, stream>>>(
        s_buf, nattr, Wread, batch, (float*)d_out, N, pool_scale);
}